// Round 2
// baseline (996.526 us; speedup 1.0000x reference)
//
#include <hip/hip_runtime.h>
#include <hip/hip_bf16.h>

#define N_NODES 50000
#define N_EDGES 800000
#define EP (N_EDGES + N_NODES)   // with self-loops
#define IN_C 128
#define HID 64
#define HEADS 2
#define LAT 32
#define NEG_SLOPE 0.2f

// ---------------- proj1: h1 = x @ W1, + per-head a_src/a_dst ----------------
// block = 128 threads (2 waves, one per head), TM=8 rows per block.
#define TM 8
__global__ __launch_bounds__(128) void proj1_kernel(
    const float* __restrict__ x, const float* __restrict__ W,
    const float* __restrict__ att_src, const float* __restrict__ att_dst,
    float* __restrict__ h1, float* __restrict__ a1) {
  __shared__ float xs[TM][IN_C];
  const int row0 = blockIdx.x * TM;
  const int o = threadIdx.x;  // 0..127 output column
  #pragma unroll
  for (int r = 0; r < TM; ++r) {
    int n = row0 + r;
    xs[r][o] = (n < N_NODES) ? x[n * IN_C + o] : 0.f;
  }
  __syncthreads();
  float acc[TM];
  #pragma unroll
  for (int r = 0; r < TM; ++r) acc[r] = 0.f;
  for (int c = 0; c < IN_C; ++c) {
    float w = W[c * 128 + o];
    #pragma unroll
    for (int r = 0; r < TM; ++r) acc[r] += xs[r][c] * w;
  }
  const int head = o >> 6, cc = o & 63;
  const float as = att_src[head * HID + cc];
  const float ad = att_dst[head * HID + cc];
  #pragma unroll
  for (int r = 0; r < TM; ++r) {
    int n = row0 + r;
    if (n < N_NODES) h1[n * 128 + o] = acc[r];
    float s = acc[r] * as, d = acc[r] * ad;
    // wave-64 reduce (wave 0 = head 0, wave 1 = head 1)
    #pragma unroll
    for (int off = 32; off; off >>= 1) {
      s += __shfl_xor(s, off);
      d += __shfl_xor(d, off);
    }
    if (cc == 0 && n < N_NODES) {
      a1[n * 4 + head] = s;       // a_src head0, head1 -> .x .y
      a1[n * 4 + 2 + head] = d;   // a_dst head0, head1 -> .z .w
    }
  }
}

// ---------------- layer-1 edge softmax denominator ----------------
// Softmax computed WITHOUT max-shift: logits ~N(0,1.3^2), exp safe in fp32;
// identical to reference modulo ~1e-6 (threshold 1.79e-2).
__global__ void edge_denom1_kernel(const int* __restrict__ ei,
                                   const float4* __restrict__ a1,
                                   float* __restrict__ denom) {
  int e = blockIdx.x * blockDim.x + threadIdx.x;
  if (e >= EP) return;
  int s, d;
  if (e < N_EDGES) { s = ei[e]; d = ei[N_EDGES + e]; }
  else { s = d = e - N_EDGES; }
  float4 av = a1[s], bv = a1[d];
  float l0 = av.x + bv.z; l0 = l0 > 0.f ? l0 : NEG_SLOPE * l0;
  float l1 = av.y + bv.w; l1 = l1 > 0.f ? l1 : NEG_SLOPE * l1;
  atomicAdd(&denom[d * 2 + 0], expf(l0));
  atomicAdd(&denom[d * 2 + 1], expf(l1));
}

// ---------------- layer-1 weighted scatter-aggregate ----------------
// one thread per (edge, channel); recompute edge weight (cheaper than storing alpha)
__global__ void agg1_kernel(const int* __restrict__ ei,
                            const float4* __restrict__ a1,
                            const float* __restrict__ denom,
                            const float* __restrict__ h1,
                            float* __restrict__ agg) {
  long long t = (long long)blockIdx.x * blockDim.x + threadIdx.x;
  if (t >= (long long)EP * 128) return;
  int e = (int)(t >> 7);
  int c = (int)(t & 127);
  int s, d;
  if (e < N_EDGES) { s = ei[e]; d = ei[N_EDGES + e]; }
  else { s = d = e - N_EDGES; }
  int head = c >> 6;
  float4 av = a1[s], bv = a1[d];
  float l = head ? (av.y + bv.w) : (av.x + bv.z);
  l = l > 0.f ? l : NEG_SLOPE * l;
  float w = expf(l) / (denom[d * 2 + head] + 1e-16f);
  atomicAdd(&agg[d * 128 + c], h1[s * 128 + c] * w);
}

// ---------------- bias + ELU (in place on agg1) ----------------
__global__ void bias_elu_kernel(float* __restrict__ agg, const float* __restrict__ b) {
  int t = blockIdx.x * blockDim.x + threadIdx.x;
  if (t >= N_NODES * 128) return;
  float v = agg[t] + b[t & 127];
  agg[t] = v > 0.f ? v : (expf(v) - 1.f);
}

// ---------------- proj2: hmu = h@Wmu, hlv = h@Wlv, + a scalars ----------------
// block = 64 threads: lanes 0..31 -> mu cols, 32..63 -> lv cols; TM rows/block
__global__ __launch_bounds__(64) void proj2_kernel(
    const float* __restrict__ h,
    const float* __restrict__ Wmu, const float* __restrict__ Wlv,
    const float* __restrict__ asmu, const float* __restrict__ admu,
    const float* __restrict__ aslv, const float* __restrict__ adlv,
    float* __restrict__ hmu, float* __restrict__ hlv, float* __restrict__ a2) {
  __shared__ float xs[TM][128];
  const int row0 = blockIdx.x * TM;
  const int t = threadIdx.x;  // 0..63
  for (int i = t; i < TM * 128; i += 64) {
    int r = i >> 7, c = i & 127;
    int n = row0 + r;
    xs[r][c] = (n < N_NODES) ? h[n * 128 + c] : 0.f;
  }
  __syncthreads();
  const int j = t >> 5;   // 0 = mu, 1 = lv
  const int o = t & 31;   // output col
  const float* W = j ? Wlv : Wmu;
  float acc[TM];
  #pragma unroll
  for (int r = 0; r < TM; ++r) acc[r] = 0.f;
  for (int c = 0; c < 128; ++c) {
    float w = W[c * LAT + o];
    #pragma unroll
    for (int r = 0; r < TM; ++r) acc[r] += xs[r][c] * w;
  }
  const float as = (j ? aslv : asmu)[o];
  const float ad = (j ? adlv : admu)[o];
  float* ho = j ? hlv : hmu;
  #pragma unroll
  for (int r = 0; r < TM; ++r) {
    int n = row0 + r;
    if (n < N_NODES) ho[n * LAT + o] = acc[r];
    float s = acc[r] * as, d = acc[r] * ad;
    // reduce within each 32-lane half (xor offsets < 32 stay in half)
    #pragma unroll
    for (int off = 16; off; off >>= 1) {
      s += __shfl_xor(s, off);
      d += __shfl_xor(d, off);
    }
    if (o == 0 && n < N_NODES) {
      a2[n * 4 + j * 2 + 0] = s;  // (asrc_mu, adst_mu, asrc_lv, adst_lv)
      a2[n * 4 + j * 2 + 1] = d;
    }
  }
}

// ---------------- layer-2 edge denominator (mu & lv share edge structure) ---
__global__ void edge_denom2_kernel(const int* __restrict__ ei,
                                   const float4* __restrict__ a2,
                                   float* __restrict__ denom) {
  int e = blockIdx.x * blockDim.x + threadIdx.x;
  if (e >= EP) return;
  int s, d;
  if (e < N_EDGES) { s = ei[e]; d = ei[N_EDGES + e]; }
  else { s = d = e - N_EDGES; }
  float4 av = a2[s], bv = a2[d];
  float l0 = av.x + bv.y; l0 = l0 > 0.f ? l0 : NEG_SLOPE * l0;  // mu
  float l1 = av.z + bv.w; l1 = l1 > 0.f ? l1 : NEG_SLOPE * l1;  // lv
  atomicAdd(&denom[d * 2 + 0], expf(l0));
  atomicAdd(&denom[d * 2 + 1], expf(l1));
}

// ---------------- layer-2 scatter-aggregate straight into d_out ------------
__global__ void agg2_kernel(const int* __restrict__ ei,
                            const float4* __restrict__ a2,
                            const float* __restrict__ denom,
                            const float* __restrict__ hmu,
                            const float* __restrict__ hlv,
                            float* __restrict__ out) {
  long long t = (long long)blockIdx.x * blockDim.x + threadIdx.x;
  if (t >= (long long)EP * 64) return;
  int e = (int)(t >> 6);
  int c = (int)(t & 63);
  int s, d;
  if (e < N_EDGES) { s = ei[e]; d = ei[N_EDGES + e]; }
  else { s = d = e - N_EDGES; }
  int j = c >> 5;       // 0 = mu, 1 = lv
  int cc = c & 31;
  float4 av = a2[s], bv = a2[d];
  float l = j ? (av.z + bv.w) : (av.x + bv.y);
  l = l > 0.f ? l : NEG_SLOPE * l;
  float w = expf(l) / (denom[d * 2 + j] + 1e-16f);
  const float* hs = j ? hlv : hmu;
  atomicAdd(&out[(size_t)j * N_NODES * LAT + d * LAT + cc], hs[s * LAT + cc] * w);
}

// ---------------- final bias add on d_out ----------------
__global__ void bias2_kernel(float* __restrict__ out,
                             const float* __restrict__ bmu,
                             const float* __restrict__ blv) {
  int t = blockIdx.x * blockDim.x + threadIdx.x;
  if (t >= 2 * N_NODES * LAT) return;
  int c = t & (LAT - 1);
  out[t] += (t < N_NODES * LAT) ? bmu[c] : blv[c];
}

extern "C" void kernel_launch(void* const* d_in, const int* in_sizes, int n_in,
                              void* d_out, int out_size, void* d_ws, size_t ws_size,
                              hipStream_t stream) {
  const float* x        = (const float*)d_in[0];
  const int* ei         = (const int*)d_in[1];   // int32 per harness contract
  const float* W1       = (const float*)d_in[2];
  const float* att_src1 = (const float*)d_in[3];
  const float* att_dst1 = (const float*)d_in[4];
  const float* b1       = (const float*)d_in[5];
  const float* Wmu      = (const float*)d_in[6];
  const float* asmu     = (const float*)d_in[7];
  const float* admu     = (const float*)d_in[8];
  const float* bmu      = (const float*)d_in[9];
  const float* Wlv      = (const float*)d_in[10];
  const float* aslv     = (const float*)d_in[11];
  const float* adlv     = (const float*)d_in[12];
  const float* blv      = (const float*)d_in[13];
  float* out = (float*)d_out;

  // workspace layout (floats):
  //   [agg1: N*128 | denom1: N*2 | denom2: N*2 | a1: N*4 | h1: N*128]
  //   hmu/hlv/a2 alias the h1 region (h1 dead after agg1).
  float* ws = (float*)d_ws;
  float* agg1   = ws;
  float* denom1 = ws + (size_t)N_NODES * 128;
  float* denom2 = denom1 + (size_t)N_NODES * 2;
  float* a1     = denom2 + (size_t)N_NODES * 2;
  float* h1     = a1 + (size_t)N_NODES * 4;
  float* hmu    = h1;                          // alias (post layer-1)
  float* hlv    = h1 + (size_t)N_NODES * LAT;
  float* a2     = h1 + (size_t)N_NODES * 2 * LAT;

  // zero agg1 + denom1 + denom2 in one contiguous memset; zero d_out (poisoned)
  hipMemsetAsync(agg1, 0, (size_t)N_NODES * 132 * sizeof(float), stream);
  hipMemsetAsync(out, 0, (size_t)out_size * sizeof(float), stream);

  // layer 1
  proj1_kernel<<<(N_NODES + TM - 1) / TM, 128, 0, stream>>>(
      x, W1, att_src1, att_dst1, h1, a1);
  edge_denom1_kernel<<<(EP + 255) / 256, 256, 0, stream>>>(
      ei, (const float4*)a1, denom1);
  {
    long long total = (long long)EP * 128;
    int blocks = (int)((total + 255) / 256);
    agg1_kernel<<<blocks, 256, 0, stream>>>(ei, (const float4*)a1, denom1, h1, agg1);
  }
  bias_elu_kernel<<<(N_NODES * 128 + 255) / 256, 256, 0, stream>>>(agg1, b1);

  // layer 2 (mu & lv fused)
  proj2_kernel<<<(N_NODES + TM - 1) / TM, 64, 0, stream>>>(
      agg1, Wmu, Wlv, asmu, admu, aslv, adlv, hmu, hlv, a2);
  edge_denom2_kernel<<<(EP + 255) / 256, 256, 0, stream>>>(
      ei, (const float4*)a2, denom2);
  {
    long long total = (long long)EP * 64;
    int blocks = (int)((total + 255) / 256);
    agg2_kernel<<<blocks, 256, 0, stream>>>(ei, (const float4*)a2, denom2, hmu, hlv, out);
  }
  bias2_kernel<<<(2 * N_NODES * LAT + 255) / 256, 256, 0, stream>>>(out, bmu, blv);
}

// Round 3
// 477.503 us; speedup vs baseline: 2.0870x; 2.0870x over previous
//
#include <hip/hip_runtime.h>
#include <hip/hip_bf16.h>

#define N_NODES 50000
#define N_EDGES 800000
#define EP (N_EDGES + N_NODES)   // with self-loops
#define IN_C 128
#define HID 64
#define HEADS 2
#define LAT 32
#define NEG_SLOPE 0.2f

// ================= CSR build (by dst), reused by both layers =================
__global__ void count_kernel(const int* __restrict__ ei, int* __restrict__ counts) {
  int e = blockIdx.x * blockDim.x + threadIdx.x;
  if (e >= EP) return;
  int d = (e < N_EDGES) ? ei[N_EDGES + e] : e - N_EDGES;
  atomicAdd(&counts[d], 1);
}

// single-block exclusive scan of counts -> offs (offs later doubles as cursor)
__global__ __launch_bounds__(1024) void scan_kernel(const int* __restrict__ counts,
                                                    int* __restrict__ offs) {
  __shared__ int wsum[16];
  __shared__ int s_carry;
  const int t = threadIdx.x, lane = t & 63, wid = t >> 6;
  if (t == 0) s_carry = 0;
  __syncthreads();
  for (int base = 0; base < N_NODES; base += 1024) {
    int i = base + t;
    int v = (i < N_NODES) ? counts[i] : 0;
    int inc = v;
    #pragma unroll
    for (int off = 1; off < 64; off <<= 1) {
      int nv = __shfl_up(inc, off);
      if (lane >= off) inc += nv;
    }
    if (lane == 63) wsum[wid] = inc;
    __syncthreads();
    if (wid == 0) {
      int w = (lane < 16) ? wsum[lane] : 0;
      #pragma unroll
      for (int off = 1; off < 16; off <<= 1) {
        int nv = __shfl_up(w, off);
        if (lane >= off) w += nv;
      }
      if (lane < 16) wsum[lane] = w;
    }
    __syncthreads();
    int carry = s_carry;
    int excl = carry + (wid ? wsum[wid - 1] : 0) + inc - v;
    if (i < N_NODES) offs[i] = excl;
    __syncthreads();                 // all reads of s_carry/wsum done
    if (t == 0) s_carry = carry + wsum[15];
    __syncthreads();
  }
}

// scatter edge src ids into CSR slots; offs acts as atomic cursor.
// after this kernel offs[n] == segment END for node n; beg = end - counts[n].
__global__ void fill_kernel(const int* __restrict__ ei, int* __restrict__ offs,
                            int* __restrict__ csr_src) {
  int e = blockIdx.x * blockDim.x + threadIdx.x;
  if (e >= EP) return;
  int s, d;
  if (e < N_EDGES) { s = ei[e]; d = ei[N_EDGES + e]; }
  else { s = d = e - N_EDGES; }
  int pos = atomicAdd(&offs[d], 1);
  csr_src[pos] = s;
}

// ---------------- proj1: h1 = x @ W1, + per-head a_src/a_dst ----------------
#define TM 8
__global__ __launch_bounds__(128) void proj1_kernel(
    const float* __restrict__ x, const float* __restrict__ W,
    const float* __restrict__ att_src, const float* __restrict__ att_dst,
    float* __restrict__ h1, float* __restrict__ a1) {
  __shared__ float xs[TM][IN_C];
  const int row0 = blockIdx.x * TM;
  const int o = threadIdx.x;  // 0..127 output column
  #pragma unroll
  for (int r = 0; r < TM; ++r) {
    int n = row0 + r;
    xs[r][o] = (n < N_NODES) ? x[n * IN_C + o] : 0.f;
  }
  __syncthreads();
  float acc[TM];
  #pragma unroll
  for (int r = 0; r < TM; ++r) acc[r] = 0.f;
  for (int c = 0; c < IN_C; ++c) {
    float w = W[c * 128 + o];
    #pragma unroll
    for (int r = 0; r < TM; ++r) acc[r] += xs[r][c] * w;
  }
  const int head = o >> 6, cc = o & 63;
  const float as = att_src[head * HID + cc];
  const float ad = att_dst[head * HID + cc];
  #pragma unroll
  for (int r = 0; r < TM; ++r) {
    int n = row0 + r;
    if (n < N_NODES) h1[n * 128 + o] = acc[r];
    float s = acc[r] * as, d = acc[r] * ad;
    #pragma unroll
    for (int off = 32; off; off >>= 1) {
      s += __shfl_xor(s, off);
      d += __shfl_xor(d, off);
    }
    if (cc == 0 && n < N_NODES) {
      a1[n * 4 + head] = s;       // a_src h0,h1 -> .x .y
      a1[n * 4 + 2 + head] = d;   // a_dst h0,h1 -> .z .w
    }
  }
}

// ---- layer-1 gather-aggregate, fused: denom + weighted sum + bias + ELU ----
// one block (128 thr) per dst node; dsum accumulates redundantly per lane
// (wave-uniform per head) so no reduction is needed.
__global__ __launch_bounds__(128) void agg1_csr_kernel(
    const int* __restrict__ counts, const int* __restrict__ cend,
    const int* __restrict__ csr_src, const float4* __restrict__ a1,
    const float* __restrict__ h1, const float* __restrict__ b,
    float* __restrict__ hact) {
  const int n = blockIdx.x;
  const int c = threadIdx.x;
  const int head = c >> 6;
  const int end = cend[n];
  const int beg = end - counts[n];
  const float4 bv = a1[n];
  const float bd = head ? bv.w : bv.z;
  float acc = 0.f, dsum = 0.f;
  for (int k = beg; k < end; ++k) {
    int s = csr_src[k];
    float4 av = a1[s];
    float l = (head ? av.y : av.x) + bd;
    l = l > 0.f ? l : NEG_SLOPE * l;
    float w = expf(l);
    dsum += w;
    acc += h1[s * 128 + c] * w;
  }
  float v = acc / (dsum + 1e-16f) + b[c];
  hact[n * 128 + c] = v > 0.f ? v : (expf(v) - 1.f);
}

// ---------------- proj2: hmu = h@Wmu, hlv = h@Wlv, + a scalars ---------------
__global__ __launch_bounds__(64) void proj2_kernel(
    const float* __restrict__ h,
    const float* __restrict__ Wmu, const float* __restrict__ Wlv,
    const float* __restrict__ asmu, const float* __restrict__ admu,
    const float* __restrict__ aslv, const float* __restrict__ adlv,
    float* __restrict__ hmu, float* __restrict__ hlv, float* __restrict__ a2) {
  __shared__ float xs[TM][128];
  const int row0 = blockIdx.x * TM;
  const int t = threadIdx.x;  // 0..63
  for (int i = t; i < TM * 128; i += 64) {
    int r = i >> 7, c = i & 127;
    int n = row0 + r;
    xs[r][c] = (n < N_NODES) ? h[n * 128 + c] : 0.f;
  }
  __syncthreads();
  const int j = t >> 5;   // 0 = mu, 1 = lv
  const int o = t & 31;
  const float* W = j ? Wlv : Wmu;
  float acc[TM];
  #pragma unroll
  for (int r = 0; r < TM; ++r) acc[r] = 0.f;
  for (int c = 0; c < 128; ++c) {
    float w = W[c * LAT + o];
    #pragma unroll
    for (int r = 0; r < TM; ++r) acc[r] += xs[r][c] * w;
  }
  const float as = (j ? aslv : asmu)[o];
  const float ad = (j ? adlv : admu)[o];
  float* ho = j ? hlv : hmu;
  #pragma unroll
  for (int r = 0; r < TM; ++r) {
    int n = row0 + r;
    if (n < N_NODES) ho[n * LAT + o] = acc[r];
    float s = acc[r] * as, d = acc[r] * ad;
    #pragma unroll
    for (int off = 16; off; off >>= 1) {
      s += __shfl_xor(s, off);
      d += __shfl_xor(d, off);
    }
    if (o == 0 && n < N_NODES) {
      a2[n * 4 + j * 2 + 0] = s;  // (asrc_mu, adst_mu, asrc_lv, adst_lv)
      a2[n * 4 + j * 2 + 1] = d;
    }
  }
}

// ---- layer-2 gather-aggregate, fused: denom + weighted sum + bias -> out ----
__global__ __launch_bounds__(64) void agg2_csr_kernel(
    const int* __restrict__ counts, const int* __restrict__ cend,
    const int* __restrict__ csr_src, const float4* __restrict__ a2,
    const float* __restrict__ hmu, const float* __restrict__ hlv,
    const float* __restrict__ bmu, const float* __restrict__ blv,
    float* __restrict__ out) {
  const int n = blockIdx.x;
  const int t = threadIdx.x;
  const int j = t >> 5, o = t & 31;   // j: 0=mu 1=lv
  const int end = cend[n];
  const int beg = end - counts[n];
  const float4 bv = a2[n];
  const float bd = j ? bv.w : bv.y;
  const float* hs = j ? hlv : hmu;
  float acc = 0.f, dsum = 0.f;
  for (int k = beg; k < end; ++k) {
    int s = csr_src[k];
    float4 av = a2[s];
    float l = (j ? av.z : av.x) + bd;
    l = l > 0.f ? l : NEG_SLOPE * l;
    float w = expf(l);
    dsum += w;
    acc += hs[s * 32 + o] * w;
  }
  out[(size_t)j * N_NODES * LAT + n * LAT + o] =
      acc / (dsum + 1e-16f) + (j ? blv : bmu)[o];
}

extern "C" void kernel_launch(void* const* d_in, const int* in_sizes, int n_in,
                              void* d_out, int out_size, void* d_ws, size_t ws_size,
                              hipStream_t stream) {
  const float* x        = (const float*)d_in[0];
  const int* ei         = (const int*)d_in[1];   // int32 per harness contract
  const float* W1       = (const float*)d_in[2];
  const float* att_src1 = (const float*)d_in[3];
  const float* att_dst1 = (const float*)d_in[4];
  const float* b1       = (const float*)d_in[5];
  const float* Wmu      = (const float*)d_in[6];
  const float* asmu     = (const float*)d_in[7];
  const float* admu     = (const float*)d_in[8];
  const float* bmu      = (const float*)d_in[9];
  const float* Wlv      = (const float*)d_in[10];
  const float* aslv     = (const float*)d_in[11];
  const float* adlv     = (const float*)d_in[12];
  const float* blv      = (const float*)d_in[13];
  float* out = (float*)d_out;

  // workspace layout:
  //   [hact: N*128 f | a1: N*4 f | h1: N*128 f | counts: N i | offs: N i | csr: EP i]
  //   hmu/hlv/a2 alias h1 after layer 1 (h1 dead once agg1 completes).
  float* ws   = (float*)d_ws;
  float* hact = ws;
  float* a1   = hact + (size_t)N_NODES * 128;
  float* h1   = a1 + (size_t)N_NODES * 4;
  float* hmu  = h1;                              // alias (post layer-1)
  float* hlv  = h1 + (size_t)N_NODES * LAT;
  float* a2   = h1 + (size_t)N_NODES * 2 * LAT;
  int* counts = (int*)(h1 + (size_t)N_NODES * 128);
  int* offs   = counts + N_NODES;
  int* csr    = offs + N_NODES;

  // only counts needs zeroing; all other buffers are fully overwritten.
  hipMemsetAsync(counts, 0, (size_t)N_NODES * sizeof(int), stream);

  // CSR build (shared by both layers)
  count_kernel<<<(EP + 255) / 256, 256, 0, stream>>>(ei, counts);
  scan_kernel<<<1, 1024, 0, stream>>>(counts, offs);
  fill_kernel<<<(EP + 255) / 256, 256, 0, stream>>>(ei, offs, csr);
  // after fill: offs[n] == csr segment end for node n

  // layer 1
  proj1_kernel<<<(N_NODES + TM - 1) / TM, 128, 0, stream>>>(
      x, W1, att_src1, att_dst1, h1, a1);
  agg1_csr_kernel<<<N_NODES, 128, 0, stream>>>(
      counts, offs, csr, (const float4*)a1, h1, b1, hact);

  // layer 2 (mu & lv fused)
  proj2_kernel<<<(N_NODES + TM - 1) / TM, 64, 0, stream>>>(
      hact, Wmu, Wlv, asmu, admu, aslv, adlv, hmu, hlv, a2);
  agg2_csr_kernel<<<N_NODES, 64, 0, stream>>>(
      counts, offs, csr, (const float4*)a2, hmu, hlv, bmu, blv, out);
}

// Round 4
// 405.988 us; speedup vs baseline: 2.4546x; 1.1762x over previous
//
#include <hip/hip_runtime.h>
#include <hip/hip_bf16.h>

#define N_NODES 50000
#define N_EDGES 800000
#define EP (N_EDGES + N_NODES)   // with self-loops
#define IN_C 128
#define HID 64
#define HEADS 2
#define LAT 32
#define NEG_SLOPE 0.2f
#define MAXDEG 256   // max in-degree; Poisson(16)+1 self-loop -> P(>60) ~ 0

// ================= CSR build (by dst), reused by both layers =================
__global__ void count_kernel(const int* __restrict__ ei, int* __restrict__ counts) {
  int e = blockIdx.x * blockDim.x + threadIdx.x;
  if (e >= EP) return;
  int d = (e < N_EDGES) ? ei[N_EDGES + e] : e - N_EDGES;
  atomicAdd(&counts[d], 1);
}

// single-block exclusive scan of counts -> offs (offs later doubles as cursor)
__global__ __launch_bounds__(1024) void scan_kernel(const int* __restrict__ counts,
                                                    int* __restrict__ offs) {
  __shared__ int wsum[16];
  __shared__ int s_carry;
  const int t = threadIdx.x, lane = t & 63, wid = t >> 6;
  if (t == 0) s_carry = 0;
  __syncthreads();
  for (int base = 0; base < N_NODES; base += 1024) {
    int i = base + t;
    int v = (i < N_NODES) ? counts[i] : 0;
    int inc = v;
    #pragma unroll
    for (int off = 1; off < 64; off <<= 1) {
      int nv = __shfl_up(inc, off);
      if (lane >= off) inc += nv;
    }
    if (lane == 63) wsum[wid] = inc;
    __syncthreads();
    if (wid == 0) {
      int w = (lane < 16) ? wsum[lane] : 0;
      #pragma unroll
      for (int off = 1; off < 16; off <<= 1) {
        int nv = __shfl_up(w, off);
        if (lane >= off) w += nv;
      }
      if (lane < 16) wsum[lane] = w;
    }
    __syncthreads();
    int carry = s_carry;
    int excl = carry + (wid ? wsum[wid - 1] : 0) + inc - v;
    if (i < N_NODES) offs[i] = excl;
    __syncthreads();
    if (t == 0) s_carry = carry + wsum[15];
    __syncthreads();
  }
}

// scatter edge src ids into CSR slots; offs acts as atomic cursor.
// after this kernel offs[n] == segment END for node n.
__global__ void fill_kernel(const int* __restrict__ ei, int* __restrict__ offs,
                            int* __restrict__ csr_src) {
  int e = blockIdx.x * blockDim.x + threadIdx.x;
  if (e >= EP) return;
  int s, d;
  if (e < N_EDGES) { s = ei[e]; d = ei[N_EDGES + e]; }
  else { s = d = e - N_EDGES; }
  int pos = atomicAdd(&offs[d], 1);
  csr_src[pos] = s;
}

// ---------------- proj1: h1 = x @ W1, + per-head a_src/a_dst ----------------
#define TM 8
__global__ __launch_bounds__(128) void proj1_kernel(
    const float* __restrict__ x, const float* __restrict__ W,
    const float* __restrict__ att_src, const float* __restrict__ att_dst,
    float* __restrict__ h1, float* __restrict__ a1) {
  __shared__ float xs[TM][IN_C];
  const int row0 = blockIdx.x * TM;
  const int o = threadIdx.x;  // 0..127 output column
  #pragma unroll
  for (int r = 0; r < TM; ++r) {
    int n = row0 + r;
    xs[r][o] = (n < N_NODES) ? x[n * IN_C + o] : 0.f;
  }
  __syncthreads();
  float acc[TM];
  #pragma unroll
  for (int r = 0; r < TM; ++r) acc[r] = 0.f;
  for (int c = 0; c < IN_C; ++c) {
    float w = W[c * 128 + o];
    #pragma unroll
    for (int r = 0; r < TM; ++r) acc[r] += xs[r][c] * w;
  }
  const int head = o >> 6, cc = o & 63;
  const float as = att_src[head * HID + cc];
  const float ad = att_dst[head * HID + cc];
  #pragma unroll
  for (int r = 0; r < TM; ++r) {
    int n = row0 + r;
    if (n < N_NODES) h1[n * 128 + o] = acc[r];
    float s = acc[r] * as, d = acc[r] * ad;
    #pragma unroll
    for (int off = 32; off; off >>= 1) {
      s += __shfl_xor(s, off);
      d += __shfl_xor(d, off);
    }
    if (cc == 0 && n < N_NODES) {
      a1[n * 4 + head] = s;       // a_src h0,h1 -> .x .y
      a1[n * 4 + 2 + head] = d;   // a_dst h0,h1 -> .z .w
    }
  }
}

// ---- layer-1 gather-aggregate: weights computed ONCE per edge (phase A,
// LDS-staged), then a tight FMA gather loop (phase B). one wave per node. ----
__global__ __launch_bounds__(64) void agg1_csr_kernel(
    const int* __restrict__ counts, const int* __restrict__ cend,
    const int* __restrict__ csr_src, const float4* __restrict__ a1,
    const float* __restrict__ h1, const float* __restrict__ b,
    float* __restrict__ hact) {
  __shared__ float w_lds[2][MAXDEG];
  __shared__ int   s_lds[MAXDEG];
  const int n = blockIdx.x;
  const int t = threadIdx.x;  // 0..63
  const int end = cend[n];
  int cnt = counts[n];
  if (cnt > MAXDEG) cnt = MAXDEG;   // never happens (safety clamp)
  const int beg = end - cnt;
  const float4 bv = a1[n];
  // phase A: per-slot weights, once per edge
  float p0 = 0.f, p1 = 0.f;
  for (int i = t; i < cnt; i += 64) {
    int s = csr_src[beg + i];
    float4 av = a1[s];
    float l0 = av.x + bv.z; l0 = l0 > 0.f ? l0 : NEG_SLOPE * l0;
    float l1 = av.y + bv.w; l1 = l1 > 0.f ? l1 : NEG_SLOPE * l1;
    float e0 = expf(l0), e1 = expf(l1);
    w_lds[0][i] = e0; w_lds[1][i] = e1; s_lds[i] = s;
    p0 += e0; p1 += e1;
  }
  #pragma unroll
  for (int off = 32; off; off >>= 1) {   // butterfly: totals in all lanes
    p0 += __shfl_xor(p0, off);
    p1 += __shfl_xor(p1, off);
  }
  __syncthreads();
  // phase B: gather h1 rows, 2 channels per thread
  const int ch = t * 2;
  const int head = ch >> 6;
  const float* hp = h1 + ch;
  float ax = 0.f, ay = 0.f;
  #pragma unroll 4
  for (int i = 0; i < cnt; ++i) {
    int s = s_lds[i];
    float w = w_lds[head][i];
    float2 hv = *(const float2*)(hp + (size_t)s * 128);
    ax += hv.x * w; ay += hv.y * w;
  }
  float inv = 1.f / ((head ? p1 : p0) + 1e-16f);
  float vx = ax * inv + b[ch];
  float vy = ay * inv + b[ch + 1];
  vx = vx > 0.f ? vx : (expf(vx) - 1.f);
  vy = vy > 0.f ? vy : (expf(vy) - 1.f);
  *(float2*)(hact + (size_t)n * 128 + ch) = make_float2(vx, vy);
}

// ---------------- proj2: h2 = [h@Wmu | h@Wlv] (n x 64), + a scalars ----------
__global__ __launch_bounds__(64) void proj2_kernel(
    const float* __restrict__ h,
    const float* __restrict__ Wmu, const float* __restrict__ Wlv,
    const float* __restrict__ asmu, const float* __restrict__ admu,
    const float* __restrict__ aslv, const float* __restrict__ adlv,
    float* __restrict__ h2, float* __restrict__ a2) {
  __shared__ float xs[TM][128];
  const int row0 = blockIdx.x * TM;
  const int t = threadIdx.x;  // 0..63
  for (int i = t; i < TM * 128; i += 64) {
    int r = i >> 7, c = i & 127;
    int n = row0 + r;
    xs[r][c] = (n < N_NODES) ? h[n * 128 + c] : 0.f;
  }
  __syncthreads();
  const int j = t >> 5;   // 0 = mu, 1 = lv
  const int o = t & 31;
  const float* W = j ? Wlv : Wmu;
  float acc[TM];
  #pragma unroll
  for (int r = 0; r < TM; ++r) acc[r] = 0.f;
  for (int c = 0; c < 128; ++c) {
    float w = W[c * LAT + o];
    #pragma unroll
    for (int r = 0; r < TM; ++r) acc[r] += xs[r][c] * w;
  }
  const float as = (j ? aslv : asmu)[o];
  const float ad = (j ? adlv : admu)[o];
  #pragma unroll
  for (int r = 0; r < TM; ++r) {
    int n = row0 + r;
    if (n < N_NODES) h2[n * 64 + j * 32 + o] = acc[r];
    float s = acc[r] * as, d = acc[r] * ad;
    #pragma unroll
    for (int off = 16; off; off >>= 1) {
      s += __shfl_xor(s, off);
      d += __shfl_xor(d, off);
    }
    if (o == 0 && n < N_NODES) {
      a2[n * 4 + j * 2 + 0] = s;  // (asrc_mu, adst_mu, asrc_lv, adst_lv)
      a2[n * 4 + j * 2 + 1] = d;
    }
  }
}

// ---- layer-2 gather-aggregate, same two-phase structure -> out (+bias) ------
__global__ __launch_bounds__(64) void agg2_csr_kernel(
    const int* __restrict__ counts, const int* __restrict__ cend,
    const int* __restrict__ csr_src, const float4* __restrict__ a2,
    const float* __restrict__ h2,
    const float* __restrict__ bmu, const float* __restrict__ blv,
    float* __restrict__ out) {
  __shared__ float w_lds[2][MAXDEG];
  __shared__ int   s_lds[MAXDEG];
  const int n = blockIdx.x;
  const int t = threadIdx.x;  // 0..63
  const int end = cend[n];
  int cnt = counts[n];
  if (cnt > MAXDEG) cnt = MAXDEG;
  const int beg = end - cnt;
  const float4 bv = a2[n];
  float p0 = 0.f, p1 = 0.f;
  for (int i = t; i < cnt; i += 64) {
    int s = csr_src[beg + i];
    float4 av = a2[s];
    float l0 = av.x + bv.y; l0 = l0 > 0.f ? l0 : NEG_SLOPE * l0;  // mu
    float l1 = av.z + bv.w; l1 = l1 > 0.f ? l1 : NEG_SLOPE * l1;  // lv
    float e0 = expf(l0), e1 = expf(l1);
    w_lds[0][i] = e0; w_lds[1][i] = e1; s_lds[i] = s;
    p0 += e0; p1 += e1;
  }
  #pragma unroll
  for (int off = 32; off; off >>= 1) {
    p0 += __shfl_xor(p0, off);
    p1 += __shfl_xor(p1, off);
  }
  __syncthreads();
  const int j = t >> 5, o = t & 31;   // j: 0=mu 1=lv ; ch = t in h2 row
  float acc = 0.f;
  #pragma unroll 4
  for (int i = 0; i < cnt; ++i) {
    int s = s_lds[i];
    acc += h2[(size_t)s * 64 + t] * w_lds[j][i];
  }
  float inv = 1.f / ((j ? p1 : p0) + 1e-16f);
  out[(size_t)j * N_NODES * LAT + (size_t)n * LAT + o] =
      acc * inv + (j ? blv : bmu)[o];
}

extern "C" void kernel_launch(void* const* d_in, const int* in_sizes, int n_in,
                              void* d_out, int out_size, void* d_ws, size_t ws_size,
                              hipStream_t stream) {
  const float* x        = (const float*)d_in[0];
  const int* ei         = (const int*)d_in[1];   // int32 per harness contract
  const float* W1       = (const float*)d_in[2];
  const float* att_src1 = (const float*)d_in[3];
  const float* att_dst1 = (const float*)d_in[4];
  const float* b1       = (const float*)d_in[5];
  const float* Wmu      = (const float*)d_in[6];
  const float* asmu     = (const float*)d_in[7];
  const float* admu     = (const float*)d_in[8];
  const float* bmu      = (const float*)d_in[9];
  const float* Wlv      = (const float*)d_in[10];
  const float* aslv     = (const float*)d_in[11];
  const float* adlv     = (const float*)d_in[12];
  const float* blv      = (const float*)d_in[13];
  float* out = (float*)d_out;

  // workspace layout:
  //   [hact: N*128 f | a1: N*4 f | h1: N*128 f | counts: N i | offs: N i | csr: EP i]
  //   h2 (N*64) + a2 (N*4) alias the h1 region after layer 1.
  float* ws   = (float*)d_ws;
  float* hact = ws;
  float* a1   = hact + (size_t)N_NODES * 128;
  float* h1   = a1 + (size_t)N_NODES * 4;
  float* h2   = h1;                              // alias (post layer-1)
  float* a2   = h1 + (size_t)N_NODES * 64;
  int* counts = (int*)(h1 + (size_t)N_NODES * 128);
  int* offs   = counts + N_NODES;
  int* csr    = offs + N_NODES;

  hipMemsetAsync(counts, 0, (size_t)N_NODES * sizeof(int), stream);

  // CSR build (shared by both layers)
  count_kernel<<<(EP + 255) / 256, 256, 0, stream>>>(ei, counts);
  scan_kernel<<<1, 1024, 0, stream>>>(counts, offs);
  fill_kernel<<<(EP + 255) / 256, 256, 0, stream>>>(ei, offs, csr);
  // after fill: offs[n] == csr segment end for node n

  // layer 1
  proj1_kernel<<<(N_NODES + TM - 1) / TM, 128, 0, stream>>>(
      x, W1, att_src1, att_dst1, h1, a1);
  agg1_csr_kernel<<<N_NODES, 64, 0, stream>>>(
      counts, offs, csr, (const float4*)a1, h1, b1, hact);

  // layer 2 (mu & lv fused)
  proj2_kernel<<<(N_NODES + TM - 1) / TM, 64, 0, stream>>>(
      hact, Wmu, Wlv, asmu, admu, aslv, adlv, h2, a2);
  agg2_csr_kernel<<<N_NODES, 64, 0, stream>>>(
      counts, offs, csr, (const float4*)a2, h2, bmu, blv, out);
}

// Round 5
// 354.454 us; speedup vs baseline: 2.8114x; 1.1454x over previous
//
#include <hip/hip_runtime.h>
#include <hip/hip_bf16.h>

#define N_NODES 50000
#define N_EDGES 800000
#define EP (N_EDGES + N_NODES)   // with self-loops
#define IN_C 128
#define HID 64
#define HEADS 2
#define LAT 32
#define NEG_SLOPE 0.2f
#define MAXDEG 256   // max in-degree; Poisson(16)+1 self-loop -> P(>60) ~ 0

// fp32 -> bf16 with round-to-nearest-even (deterministic, no NaN inputs here)
__device__ __forceinline__ unsigned short f2bf(float f) {
  unsigned u = __float_as_uint(f);
  u += 0x7FFF + ((u >> 16) & 1);
  return (unsigned short)(u >> 16);
}
__device__ __forceinline__ float bf_lo(unsigned u) {   // low bf16 of packed pair
  return __uint_as_float(u << 16);
}
__device__ __forceinline__ float bf_hi(unsigned u) {   // high bf16 of packed pair
  return __uint_as_float(u & 0xFFFF0000u);
}

// ================= CSR build (by dst), reused by both layers =================
__global__ void count_kernel(const int* __restrict__ ei, int* __restrict__ counts) {
  int e = blockIdx.x * blockDim.x + threadIdx.x;
  if (e >= EP) return;
  int d = (e < N_EDGES) ? ei[N_EDGES + e] : e - N_EDGES;
  atomicAdd(&counts[d], 1);
}

// segment allocation: block-local scan + ONE atomic per block on a global
// cursor. Segment order across nodes is irrelevant (only disjointness +
// contiguity matter), so no ordered scan is needed.
__global__ __launch_bounds__(256) void alloc_kernel(
    const int* __restrict__ counts, int* __restrict__ offs,
    int* __restrict__ cursor) {
  __shared__ int wtot[4];
  __shared__ int wpre[4];
  __shared__ int base_s;
  const int t = threadIdx.x, lane = t & 63, wid = t >> 6;
  const int i = blockIdx.x * 256 + t;
  int v = (i < N_NODES) ? counts[i] : 0;
  int inc = v;
  #pragma unroll
  for (int off = 1; off < 64; off <<= 1) {
    int nv = __shfl_up(inc, off);
    if (lane >= off) inc += nv;
  }
  if (lane == 63) wtot[wid] = inc;
  __syncthreads();
  if (t == 0) {
    int run = 0;
    #pragma unroll
    for (int w = 0; w < 4; ++w) { wpre[w] = run; run += wtot[w]; }
    base_s = atomicAdd(cursor, run);
  }
  __syncthreads();
  if (i < N_NODES) offs[i] = base_s + wpre[wid] + inc - v;   // exclusive start
}

// scatter edge src ids into CSR slots; offs acts as atomic cursor.
// after this kernel offs[n] == segment END for node n.
__global__ void fill_kernel(const int* __restrict__ ei, int* __restrict__ offs,
                            int* __restrict__ csr_src) {
  int e = blockIdx.x * blockDim.x + threadIdx.x;
  if (e >= EP) return;
  int s, d;
  if (e < N_EDGES) { s = ei[e]; d = ei[N_EDGES + e]; }
  else { s = d = e - N_EDGES; }
  int pos = atomicAdd(&offs[d], 1);
  csr_src[pos] = s;
}

// ---------------- proj1: h1b(bf16) = x @ W1, + per-head a_src/a_dst ---------
// W tile staged in LDS (lane-stride-1 reads, conflict-free, reused over TM
// rows); x read via block-uniform addresses -> scalar loads (SMEM pipe).
#define TM 8
#define CT 32   // c-tile
__global__ __launch_bounds__(128) void proj1_kernel(
    const float* __restrict__ x, const float* __restrict__ W,
    const float* __restrict__ att_src, const float* __restrict__ att_dst,
    unsigned short* __restrict__ h1b, float* __restrict__ a1) {
  __shared__ float Wl[CT * 128];
  const int row0 = blockIdx.x * TM;       // N divisible by TM: no tail
  const int o = threadIdx.x;              // 0..127 output column
  float acc[TM];
  #pragma unroll
  for (int r = 0; r < TM; ++r) acc[r] = 0.f;
  for (int ct = 0; ct < IN_C; ct += CT) {
    // stage W[ct..ct+CT) rows (CT*128 floats) via float4, coalesced
    const float4* Wg4 = (const float4*)(W + ct * 128);
    float4* Wl4 = (float4*)Wl;
    #pragma unroll
    for (int i = 0; i < CT * 32 / 128; ++i)    // CT*128/4 float4s / 128 thr
      Wl4[i * 128 + o] = Wg4[i * 128 + o];
    __syncthreads();
    const float* xb = x + (size_t)row0 * IN_C + ct;   // uniform base
    for (int cc = 0; cc < CT; cc += 4) {
      float xv[TM][4];
      #pragma unroll
      for (int r = 0; r < TM; ++r)
        *(float4*)xv[r] = *(const float4*)(xb + r * IN_C + cc);  // uniform -> s_load
      #pragma unroll
      for (int c4 = 0; c4 < 4; ++c4) {
        float w = Wl[(cc + c4) * 128 + o];
        #pragma unroll
        for (int r = 0; r < TM; ++r) acc[r] += xv[r][c4] * w;
      }
    }
    __syncthreads();
  }
  const int head = o >> 6, cc2 = o & 63;
  const float as = att_src[head * HID + cc2];
  const float ad = att_dst[head * HID + cc2];
  #pragma unroll
  for (int r = 0; r < TM; ++r) {
    int n = row0 + r;
    h1b[(size_t)n * 128 + o] = f2bf(acc[r]);
    float s = acc[r] * as, d = acc[r] * ad;
    #pragma unroll
    for (int off = 32; off; off >>= 1) {
      s += __shfl_xor(s, off);
      d += __shfl_xor(d, off);
    }
    if (cc2 == 0) {
      a1[n * 4 + head] = s;       // a_src h0,h1 -> .x .y
      a1[n * 4 + 2 + head] = d;   // a_dst h0,h1 -> .z .w
    }
  }
}

// ---- layer-1 gather-aggregate: weights once per edge (phase A, LDS), then
// tight bf16-gather FMA loop (phase B). one wave per node. ----
__global__ __launch_bounds__(64) void agg1_csr_kernel(
    const int* __restrict__ counts, const int* __restrict__ cend,
    const int* __restrict__ csr_src, const float4* __restrict__ a1,
    const unsigned* __restrict__ h1b2,   // h1 as packed bf16 pairs
    const float* __restrict__ b, float* __restrict__ hact) {
  __shared__ float w_lds[2][MAXDEG];
  __shared__ int   s_lds[MAXDEG];
  const int n = blockIdx.x;
  const int t = threadIdx.x;  // 0..63
  const int end = cend[n];
  int cnt = counts[n];
  if (cnt > MAXDEG) cnt = MAXDEG;   // never happens (safety clamp)
  const int beg = end - cnt;
  const float4 bv = a1[n];
  float p0 = 0.f, p1 = 0.f;
  for (int i = t; i < cnt; i += 64) {
    int s = csr_src[beg + i];
    float4 av = a1[s];
    float l0 = av.x + bv.z; l0 = l0 > 0.f ? l0 : NEG_SLOPE * l0;
    float l1 = av.y + bv.w; l1 = l1 > 0.f ? l1 : NEG_SLOPE * l1;
    float e0 = expf(l0), e1 = expf(l1);
    w_lds[0][i] = e0; w_lds[1][i] = e1; s_lds[i] = s;
    p0 += e0; p1 += e1;
  }
  #pragma unroll
  for (int off = 32; off; off >>= 1) {   // butterfly: totals in all lanes
    p0 += __shfl_xor(p0, off);
    p1 += __shfl_xor(p1, off);
  }
  __syncthreads();
  // phase B: channels (2t, 2t+1); one packed-bf16-pair load per edge
  const int head = t >> 5;
  const unsigned* hp = h1b2 + t;
  float ax = 0.f, ay = 0.f;
  #pragma unroll 4
  for (int i = 0; i < cnt; ++i) {
    int s = s_lds[i];
    float w = w_lds[head][i];
    unsigned u = hp[(size_t)s * 64];
    ax += bf_lo(u) * w; ay += bf_hi(u) * w;
  }
  float inv = 1.f / ((head ? p1 : p0) + 1e-16f);
  float vx = ax * inv + b[t * 2];
  float vy = ay * inv + b[t * 2 + 1];
  vx = vx > 0.f ? vx : (expf(vx) - 1.f);
  vy = vy > 0.f ? vy : (expf(vy) - 1.f);
  *(float2*)(hact + (size_t)n * 128 + t * 2) = make_float2(vx, vy);
}

// ------- proj2: h2b(bf16) = [h@Wmu | h@Wlv] (n x 64), + a scalars -----------
// same structure: combined W tile in LDS, uniform scalar x loads.
__global__ __launch_bounds__(64) void proj2_kernel(
    const float* __restrict__ h,
    const float* __restrict__ Wmu, const float* __restrict__ Wlv,
    const float* __restrict__ asmu, const float* __restrict__ admu,
    const float* __restrict__ aslv, const float* __restrict__ adlv,
    unsigned short* __restrict__ h2b, float* __restrict__ a2) {
  __shared__ float Wl[CT * 64];
  const int row0 = blockIdx.x * TM;
  const int t = threadIdx.x;  // 0..63
  const int j = t >> 5;       // 0 = mu, 1 = lv
  const int o = t & 31;
  const float* Wsel = j ? Wlv : Wmu;
  float acc[TM];
  #pragma unroll
  for (int r = 0; r < TM; ++r) acc[r] = 0.f;
  for (int ct = 0; ct < 128; ct += CT) {
    #pragma unroll
    for (int i = 0; i < CT; ++i)           // Wl[c][t]: half-wave rows of Wmu/Wlv
      Wl[i * 64 + t] = Wsel[(ct + i) * LAT + o];
    __syncthreads();
    const float* xb = h + (size_t)row0 * 128 + ct;  // uniform
    for (int cc = 0; cc < CT; cc += 4) {
      float xv[TM][4];
      #pragma unroll
      for (int r = 0; r < TM; ++r)
        *(float4*)xv[r] = *(const float4*)(xb + r * 128 + cc);
      #pragma unroll
      for (int c4 = 0; c4 < 4; ++c4) {
        float w = Wl[(cc + c4) * 64 + t];
        #pragma unroll
        for (int r = 0; r < TM; ++r) acc[r] += xv[r][c4] * w;
      }
    }
    __syncthreads();
  }
  const float as = (j ? aslv : asmu)[o];
  const float ad = (j ? adlv : admu)[o];
  #pragma unroll
  for (int r = 0; r < TM; ++r) {
    int n = row0 + r;
    h2b[(size_t)n * 64 + t] = f2bf(acc[r]);
    float s = acc[r] * as, d = acc[r] * ad;
    #pragma unroll
    for (int off = 16; off; off >>= 1) {   // reduce within 32-lane half
      s += __shfl_xor(s, off);
      d += __shfl_xor(d, off);
    }
    if (o == 0) {
      a2[n * 4 + j * 2 + 0] = s;  // (asrc_mu, adst_mu, asrc_lv, adst_lv)
      a2[n * 4 + j * 2 + 1] = d;
    }
  }
}

// ---- layer-2 gather-aggregate, same two-phase structure -> out (+bias) ------
__global__ __launch_bounds__(64) void agg2_csr_kernel(
    const int* __restrict__ counts, const int* __restrict__ cend,
    const int* __restrict__ csr_src, const float4* __restrict__ a2,
    const unsigned short* __restrict__ h2b,
    const float* __restrict__ bmu, const float* __restrict__ blv,
    float* __restrict__ out) {
  __shared__ float w_lds[2][MAXDEG];
  __shared__ int   s_lds[MAXDEG];
  const int n = blockIdx.x;
  const int t = threadIdx.x;  // 0..63
  const int end = cend[n];
  int cnt = counts[n];
  if (cnt > MAXDEG) cnt = MAXDEG;
  const int beg = end - cnt;
  const float4 bv = a2[n];
  float p0 = 0.f, p1 = 0.f;
  for (int i = t; i < cnt; i += 64) {
    int s = csr_src[beg + i];
    float4 av = a2[s];
    float l0 = av.x + bv.y; l0 = l0 > 0.f ? l0 : NEG_SLOPE * l0;  // mu
    float l1 = av.z + bv.w; l1 = l1 > 0.f ? l1 : NEG_SLOPE * l1;  // lv
    float e0 = expf(l0), e1 = expf(l1);
    w_lds[0][i] = e0; w_lds[1][i] = e1; s_lds[i] = s;
    p0 += e0; p1 += e1;
  }
  #pragma unroll
  for (int off = 32; off; off >>= 1) {
    p0 += __shfl_xor(p0, off);
    p1 += __shfl_xor(p1, off);
  }
  __syncthreads();
  const int j = t >> 5, o = t & 31;   // j: 0=mu 1=lv ; channel t of h2 row
  const unsigned short* hp = h2b + t;
  float acc = 0.f;
  #pragma unroll 4
  for (int i = 0; i < cnt; ++i) {
    int s = s_lds[i];
    float hv = __uint_as_float(((unsigned)hp[(size_t)s * 64]) << 16);
    acc += hv * w_lds[j][i];
  }
  float inv = 1.f / ((j ? p1 : p0) + 1e-16f);
  out[(size_t)j * N_NODES * LAT + (size_t)n * LAT + o] =
      acc * inv + (j ? blv : bmu)[o];
}

extern "C" void kernel_launch(void* const* d_in, const int* in_sizes, int n_in,
                              void* d_out, int out_size, void* d_ws, size_t ws_size,
                              hipStream_t stream) {
  const float* x        = (const float*)d_in[0];
  const int* ei         = (const int*)d_in[1];   // int32 per harness contract
  const float* W1       = (const float*)d_in[2];
  const float* att_src1 = (const float*)d_in[3];
  const float* att_dst1 = (const float*)d_in[4];
  const float* b1       = (const float*)d_in[5];
  const float* Wmu      = (const float*)d_in[6];
  const float* asmu     = (const float*)d_in[7];
  const float* admu     = (const float*)d_in[8];
  const float* bmu      = (const float*)d_in[9];
  const float* Wlv      = (const float*)d_in[10];
  const float* aslv     = (const float*)d_in[11];
  const float* adlv     = (const float*)d_in[12];
  const float* blv      = (const float*)d_in[13];
  float* out = (float*)d_out;

  // workspace layout (4-B units):
  //  [hact N*128 | a1 N*4 | a2 N*4 | h1b N*64(bf16 pairs) | h2b N*32 |
  //   counts N | cursor 1 | offs N | csr EP]
  float* ws   = (float*)d_ws;
  float* hact = ws;
  float* a1   = hact + (size_t)N_NODES * 128;
  float* a2   = a1 + (size_t)N_NODES * 4;
  unsigned short* h1b = (unsigned short*)(a2 + (size_t)N_NODES * 4);
  unsigned short* h2b = h1b + (size_t)N_NODES * 128;
  int* counts = (int*)(h2b + (size_t)N_NODES * 64);
  int* cursor = counts + N_NODES;
  int* offs   = cursor + 1;
  int* csr    = offs + N_NODES;

  // zero counts + cursor in one memset
  hipMemsetAsync(counts, 0, (size_t)(N_NODES + 1) * sizeof(int), stream);

  // CSR build (shared by both layers)
  count_kernel<<<(EP + 255) / 256, 256, 0, stream>>>(ei, counts);
  alloc_kernel<<<(N_NODES + 255) / 256, 256, 0, stream>>>(counts, offs, cursor);
  fill_kernel<<<(EP + 255) / 256, 256, 0, stream>>>(ei, offs, csr);
  // after fill: offs[n] == csr segment end for node n

  // layer 1
  proj1_kernel<<<N_NODES / TM, 128, 0, stream>>>(
      x, W1, att_src1, att_dst1, h1b, a1);
  agg1_csr_kernel<<<N_NODES, 64, 0, stream>>>(
      counts, offs, csr, (const float4*)a1, (const unsigned*)h1b, b1, hact);

  // layer 2 (mu & lv fused)
  proj2_kernel<<<N_NODES / TM, 64, 0, stream>>>(
      hact, Wmu, Wlv, asmu, admu, aslv, adlv, h2b, a2);
  agg2_csr_kernel<<<N_NODES, 64, 0, stream>>>(
      counts, offs, csr, (const float4*)a2, h2b, bmu, blv, out);
}

// Round 6
// 311.842 us; speedup vs baseline: 3.1956x; 1.1366x over previous
//
#include <hip/hip_runtime.h>
#include <hip/hip_bf16.h>

#define N_NODES 50000
#define N_EDGES 800000
#define EP (N_EDGES + N_NODES)   // with self-loops
#define IN_C 128
#define HID 64
#define HEADS 2
#define LAT 32
#define NEG_SLOPE 0.2f
#define MAXDEG 256   // max in-degree; Poisson(16)+1 self-loop -> P(>60) ~ 0

typedef __attribute__((ext_vector_type(8))) short bf16x8;
typedef __attribute__((ext_vector_type(4))) float f32x4;

// fp32 -> bf16 round-to-nearest-even
__device__ __forceinline__ unsigned short f2bf(float f) {
  unsigned u = __float_as_uint(f);
  u += 0x7FFF + ((u >> 16) & 1);
  return (unsigned short)(u >> 16);
}
__device__ __forceinline__ float bf_lo(unsigned u) { return __uint_as_float(u << 16); }
__device__ __forceinline__ float bf_hi(unsigned u) { return __uint_as_float(u & 0xFFFF0000u); }

// load 8 contiguous fp32, convert to a bf16x8 A-fragment
__device__ __forceinline__ bf16x8 pack_bf8(const float* __restrict__ p) {
  float4 a = *(const float4*)p;
  float4 b = *(const float4*)(p + 4);
  bf16x8 r;
  r[0] = (short)f2bf(a.x); r[1] = (short)f2bf(a.y);
  r[2] = (short)f2bf(a.z); r[3] = (short)f2bf(a.w);
  r[4] = (short)f2bf(b.x); r[5] = (short)f2bf(b.y);
  r[6] = (short)f2bf(b.z); r[7] = (short)f2bf(b.w);
  return r;
}

// ================= CSR build (by dst), reused by both layers =================
__global__ void count_kernel(const int* __restrict__ ei, int* __restrict__ counts) {
  int e = blockIdx.x * blockDim.x + threadIdx.x;
  if (e >= EP) return;
  int d = (e < N_EDGES) ? ei[N_EDGES + e] : e - N_EDGES;
  atomicAdd(&counts[d], 1);
}

// segment allocation: block-local scan + ONE atomic per block on a global
// cursor (segment order across nodes is irrelevant).
__global__ __launch_bounds__(256) void alloc_kernel(
    const int* __restrict__ counts, int* __restrict__ offs,
    int* __restrict__ cursor) {
  __shared__ int wtot[4];
  __shared__ int wpre[4];
  __shared__ int base_s;
  const int t = threadIdx.x, lane = t & 63, wid = t >> 6;
  const int i = blockIdx.x * 256 + t;
  int v = (i < N_NODES) ? counts[i] : 0;
  int inc = v;
  #pragma unroll
  for (int off = 1; off < 64; off <<= 1) {
    int nv = __shfl_up(inc, off);
    if (lane >= off) inc += nv;
  }
  if (lane == 63) wtot[wid] = inc;
  __syncthreads();
  if (t == 0) {
    int run = 0;
    #pragma unroll
    for (int w = 0; w < 4; ++w) { wpre[w] = run; run += wtot[w]; }
    base_s = atomicAdd(cursor, run);
  }
  __syncthreads();
  if (i < N_NODES) offs[i] = base_s + wpre[wid] + inc - v;   // exclusive start
}

// scatter edge src ids into CSR slots; offs acts as atomic cursor.
// after this kernel offs[n] == segment END for node n.
__global__ void fill_kernel(const int* __restrict__ ei, int* __restrict__ offs,
                            int* __restrict__ csr_src) {
  int e = blockIdx.x * blockDim.x + threadIdx.x;
  if (e >= EP) return;
  int s, d;
  if (e < N_EDGES) { s = ei[e]; d = ei[N_EDGES + e]; }
  else { s = d = e - N_EDGES; }
  int pos = atomicAdd(&offs[d], 1);
  csr_src[pos] = s;
}

// ------------- proj1 (MFMA): h1b(bf16) = x @ W1  (50000x128 @ 128x128) ------
// 256 thr = 4 waves; block tile M=32, full N=128 (wave w: n0=w*32).
// W packed once/block into LDS in B-fragment layout: [(kk*4+q)*128+n]*8+j.
__global__ __launch_bounds__(256) void proj1_kernel(
    const float* __restrict__ x, const float* __restrict__ W,
    unsigned short* __restrict__ h1b) {
  __shared__ unsigned short Wb[16384];   // 32 KB
  const int t = threadIdx.x;
  for (int i = t; i < 128 * 128; i += 256) {
    int k = i >> 7, n = i & 127;
    int kk = k >> 5, q = (k >> 3) & 3, j = k & 7;
    Wb[((((kk << 2) + q) << 7) + n) * 8 + j] = f2bf(W[i]);
  }
  __syncthreads();
  const int w = t >> 6, lane = t & 63;
  const int m = lane & 15, quad = lane >> 4;
  const int row0 = blockIdx.x * 32;
  const int n0 = w * 32;
  f32x4 acc[2][2] = {};   // [mtile][ntile]
  #pragma unroll
  for (int kk = 0; kk < 4; ++kk) {
    bf16x8 afr[2], bfr[2];
    #pragma unroll
    for (int mt = 0; mt < 2; ++mt) {
      int row = row0 + mt * 16 + m;
      if (row >= N_NODES) row = N_NODES - 1;   // clamp (discarded on store)
      afr[mt] = pack_bf8(x + (size_t)row * 128 + kk * 32 + quad * 8);
    }
    #pragma unroll
    for (int nt = 0; nt < 2; ++nt)
      bfr[nt] = *(const bf16x8*)&Wb[((((kk << 2) + quad) << 7) + n0 + nt * 16 + m) * 8];
    #pragma unroll
    for (int mt = 0; mt < 2; ++mt)
      #pragma unroll
      for (int nt = 0; nt < 2; ++nt)
        acc[mt][nt] = __builtin_amdgcn_mfma_f32_16x16x32_bf16(
            afr[mt], bfr[nt], acc[mt][nt], 0, 0, 0);
  }
  // D layout: col = n0+nt*16+(lane&15), row = quad*4+reg
  #pragma unroll
  for (int mt = 0; mt < 2; ++mt)
    #pragma unroll
    for (int r = 0; r < 4; ++r) {
      int row = row0 + mt * 16 + quad * 4 + r;
      if (row < N_NODES) {
        #pragma unroll
        for (int nt = 0; nt < 2; ++nt)
          h1b[(size_t)row * 128 + n0 + nt * 16 + m] = f2bf(acc[mt][nt][r]);
      }
    }
}

// --------- a1 pass: a1[n] = (as_h0, as_h1, ad_h0, ad_h1) from bf16 h1 -------
__global__ __launch_bounds__(256) void a1_kernel(
    const unsigned* __restrict__ h1b2, const float* __restrict__ att_src,
    const float* __restrict__ att_dst, float* __restrict__ a1) {
  const int n = blockIdx.x * 4 + (threadIdx.x >> 6);
  const int lane = threadIdx.x & 63;
  unsigned u = h1b2[(size_t)n * 64 + lane];
  float h0 = bf_lo(u), h1v = bf_hi(u);
  int head = lane >> 5;              // channels 2*lane,2*lane+1 ; head = c>>6
  int cc = (lane * 2) & 63;
  float s = h0 * att_src[head * HID + cc] + h1v * att_src[head * HID + cc + 1];
  float d = h0 * att_dst[head * HID + cc] + h1v * att_dst[head * HID + cc + 1];
  #pragma unroll
  for (int off = 16; off; off >>= 1) {   // reduce within 32-lane halves
    s += __shfl_xor(s, off);
    d += __shfl_xor(d, off);
  }
  if ((lane & 31) == 0) {
    a1[n * 4 + head] = s;
    a1[n * 4 + 2 + head] = d;
  }
}

// ---- layer-1 gather-aggregate (unchanged R4): weights once per edge (LDS),
// tight bf16-pair gather FMA loop. one wave per node. ----
__global__ __launch_bounds__(64) void agg1_csr_kernel(
    const int* __restrict__ counts, const int* __restrict__ cend,
    const int* __restrict__ csr_src, const float4* __restrict__ a1,
    const unsigned* __restrict__ h1b2, const float* __restrict__ b,
    float* __restrict__ hact) {
  __shared__ float w_lds[2][MAXDEG];
  __shared__ int   s_lds[MAXDEG];
  const int n = blockIdx.x;
  const int t = threadIdx.x;  // 0..63
  const int end = cend[n];
  int cnt = counts[n];
  if (cnt > MAXDEG) cnt = MAXDEG;
  const int beg = end - cnt;
  const float4 bv = a1[n];
  float p0 = 0.f, p1 = 0.f;
  for (int i = t; i < cnt; i += 64) {
    int s = csr_src[beg + i];
    float4 av = a1[s];
    float l0 = av.x + bv.z; l0 = l0 > 0.f ? l0 : NEG_SLOPE * l0;
    float l1 = av.y + bv.w; l1 = l1 > 0.f ? l1 : NEG_SLOPE * l1;
    float e0 = expf(l0), e1 = expf(l1);
    w_lds[0][i] = e0; w_lds[1][i] = e1; s_lds[i] = s;
    p0 += e0; p1 += e1;
  }
  #pragma unroll
  for (int off = 32; off; off >>= 1) {
    p0 += __shfl_xor(p0, off);
    p1 += __shfl_xor(p1, off);
  }
  __syncthreads();
  const int head = t >> 5;
  const unsigned* hp = h1b2 + t;
  float ax = 0.f, ay = 0.f;
  #pragma unroll 4
  for (int i = 0; i < cnt; ++i) {
    int s = s_lds[i];
    float w = w_lds[head][i];
    unsigned u = hp[(size_t)s * 64];
    ax += bf_lo(u) * w; ay += bf_hi(u) * w;
  }
  float inv = 1.f / ((head ? p1 : p0) + 1e-16f);
  float vx = ax * inv + b[t * 2];
  float vy = ay * inv + b[t * 2 + 1];
  vx = vx > 0.f ? vx : (expf(vx) - 1.f);
  vy = vy > 0.f ? vy : (expf(vy) - 1.f);
  *(float2*)(hact + (size_t)n * 128 + t * 2) = make_float2(vx, vy);
}

// ------- proj2 (MFMA): h2b(bf16) = hact @ [Wmu|Wlv]  (50000x128 @ 128x64) ---
// 256 thr = 4 waves; block tile M=64, N=64. wave w: rows (w>>1)*32, n0=(w&1)*32.
__global__ __launch_bounds__(256) void proj2_kernel(
    const float* __restrict__ h, const float* __restrict__ Wmu,
    const float* __restrict__ Wlv, unsigned short* __restrict__ h2b) {
  __shared__ unsigned short Wb[8192];   // 16 KB, [(kk*4+q)*64+n]*8+j
  const int t = threadIdx.x;
  for (int i = t; i < 128 * 64; i += 256) {
    int k = i >> 6, n = i & 63;
    float v = (n < 32) ? Wmu[k * 32 + n] : Wlv[k * 32 + (n - 32)];
    int kk = k >> 5, q = (k >> 3) & 3, j = k & 7;
    Wb[((((kk << 2) + q) << 6) + n) * 8 + j] = f2bf(v);
  }
  __syncthreads();
  const int w = t >> 6, lane = t & 63;
  const int m = lane & 15, quad = lane >> 4;
  const int row0 = blockIdx.x * 64 + (w >> 1) * 32;
  const int n0 = (w & 1) * 32;
  f32x4 acc[2][2] = {};
  #pragma unroll
  for (int kk = 0; kk < 4; ++kk) {
    bf16x8 afr[2], bfr[2];
    #pragma unroll
    for (int mt = 0; mt < 2; ++mt) {
      int row = row0 + mt * 16 + m;
      if (row >= N_NODES) row = N_NODES - 1;
      afr[mt] = pack_bf8(h + (size_t)row * 128 + kk * 32 + quad * 8);
    }
    #pragma unroll
    for (int nt = 0; nt < 2; ++nt)
      bfr[nt] = *(const bf16x8*)&Wb[((((kk << 2) + quad) << 6) + n0 + nt * 16 + m) * 8];
    #pragma unroll
    for (int mt = 0; mt < 2; ++mt)
      #pragma unroll
      for (int nt = 0; nt < 2; ++nt)
        acc[mt][nt] = __builtin_amdgcn_mfma_f32_16x16x32_bf16(
            afr[mt], bfr[nt], acc[mt][nt], 0, 0, 0);
  }
  #pragma unroll
  for (int mt = 0; mt < 2; ++mt)
    #pragma unroll
    for (int r = 0; r < 4; ++r) {
      int row = row0 + mt * 16 + quad * 4 + r;
      if (row < N_NODES) {
        #pragma unroll
        for (int nt = 0; nt < 2; ++nt)
          h2b[(size_t)row * 64 + n0 + nt * 16 + m] = f2bf(acc[mt][nt][r]);
      }
    }
}

// --------- a2 pass: a2[n] = (as_mu, ad_mu, as_lv, ad_lv) from bf16 h2 -------
__global__ __launch_bounds__(256) void a2_kernel(
    const unsigned short* __restrict__ h2b, const float* __restrict__ asmu,
    const float* __restrict__ admu, const float* __restrict__ aslv,
    const float* __restrict__ adlv, float* __restrict__ a2) {
  const int n = blockIdx.x * 4 + (threadIdx.x >> 6);
  const int lane = threadIdx.x & 63;
  float h = __uint_as_float(((unsigned)h2b[(size_t)n * 64 + lane]) << 16);
  int j = lane >> 5, o = lane & 31;
  float s = h * (j ? aslv : asmu)[o];
  float d = h * (j ? adlv : admu)[o];
  #pragma unroll
  for (int off = 16; off; off >>= 1) {
    s += __shfl_xor(s, off);
    d += __shfl_xor(d, off);
  }
  if (o == 0) {
    a2[n * 4 + j * 2 + 0] = s;
    a2[n * 4 + j * 2 + 1] = d;
  }
}

// ---- layer-2 gather-aggregate (unchanged R4) -> out (+bias) ----------------
__global__ __launch_bounds__(64) void agg2_csr_kernel(
    const int* __restrict__ counts, const int* __restrict__ cend,
    const int* __restrict__ csr_src, const float4* __restrict__ a2,
    const unsigned short* __restrict__ h2b,
    const float* __restrict__ bmu, const float* __restrict__ blv,
    float* __restrict__ out) {
  __shared__ float w_lds[2][MAXDEG];
  __shared__ int   s_lds[MAXDEG];
  const int n = blockIdx.x;
  const int t = threadIdx.x;  // 0..63
  const int end = cend[n];
  int cnt = counts[n];
  if (cnt > MAXDEG) cnt = MAXDEG;
  const int beg = end - cnt;
  const float4 bv = a2[n];
  float p0 = 0.f, p1 = 0.f;
  for (int i = t; i < cnt; i += 64) {
    int s = csr_src[beg + i];
    float4 av = a2[s];
    float l0 = av.x + bv.y; l0 = l0 > 0.f ? l0 : NEG_SLOPE * l0;  // mu
    float l1 = av.z + bv.w; l1 = l1 > 0.f ? l1 : NEG_SLOPE * l1;  // lv
    float e0 = expf(l0), e1 = expf(l1);
    w_lds[0][i] = e0; w_lds[1][i] = e1; s_lds[i] = s;
    p0 += e0; p1 += e1;
  }
  #pragma unroll
  for (int off = 32; off; off >>= 1) {
    p0 += __shfl_xor(p0, off);
    p1 += __shfl_xor(p1, off);
  }
  __syncthreads();
  const int j = t >> 5, o = t & 31;
  const unsigned short* hp = h2b + t;
  float acc = 0.f;
  #pragma unroll 4
  for (int i = 0; i < cnt; ++i) {
    int s = s_lds[i];
    float hv = __uint_as_float(((unsigned)hp[(size_t)s * 64]) << 16);
    acc += hv * w_lds[j][i];
  }
  float inv = 1.f / ((j ? p1 : p0) + 1e-16f);
  out[(size_t)j * N_NODES * LAT + (size_t)n * LAT + o] =
      acc * inv + (j ? blv : bmu)[o];
}

extern "C" void kernel_launch(void* const* d_in, const int* in_sizes, int n_in,
                              void* d_out, int out_size, void* d_ws, size_t ws_size,
                              hipStream_t stream) {
  const float* x        = (const float*)d_in[0];
  const int* ei         = (const int*)d_in[1];   // int32 per harness contract
  const float* W1       = (const float*)d_in[2];
  const float* att_src1 = (const float*)d_in[3];
  const float* att_dst1 = (const float*)d_in[4];
  const float* b1       = (const float*)d_in[5];
  const float* Wmu      = (const float*)d_in[6];
  const float* asmu     = (const float*)d_in[7];
  const float* admu     = (const float*)d_in[8];
  const float* bmu      = (const float*)d_in[9];
  const float* Wlv      = (const float*)d_in[10];
  const float* aslv     = (const float*)d_in[11];
  const float* adlv     = (const float*)d_in[12];
  const float* blv      = (const float*)d_in[13];
  float* out = (float*)d_out;

  // workspace layout (4-B units):
  //  [hact N*128 | a1 N*4 | a2 N*4 | h1b N*64(bf16 pairs) | h2b N*32 |
  //   counts N | cursor 1 | offs N | csr EP]
  float* ws   = (float*)d_ws;
  float* hact = ws;
  float* a1   = hact + (size_t)N_NODES * 128;
  float* a2   = a1 + (size_t)N_NODES * 4;
  unsigned short* h1b = (unsigned short*)(a2 + (size_t)N_NODES * 4);
  unsigned short* h2b = h1b + (size_t)N_NODES * 128;
  int* counts = (int*)(h2b + (size_t)N_NODES * 64);
  int* cursor = counts + N_NODES;
  int* offs   = cursor + 1;
  int* csr    = offs + N_NODES;

  hipMemsetAsync(counts, 0, (size_t)(N_NODES + 1) * sizeof(int), stream);

  // CSR build (shared by both layers)
  count_kernel<<<(EP + 255) / 256, 256, 0, stream>>>(ei, counts);
  alloc_kernel<<<(N_NODES + 255) / 256, 256, 0, stream>>>(counts, offs, cursor);
  fill_kernel<<<(EP + 255) / 256, 256, 0, stream>>>(ei, offs, csr);
  // after fill: offs[n] == csr segment end for node n

  // layer 1
  proj1_kernel<<<(N_NODES + 31) / 32, 256, 0, stream>>>(x, W1, h1b);
  a1_kernel<<<N_NODES / 4, 256, 0, stream>>>(
      (const unsigned*)h1b, att_src1, att_dst1, a1);
  agg1_csr_kernel<<<N_NODES, 64, 0, stream>>>(
      counts, offs, csr, (const float4*)a1, (const unsigned*)h1b, b1, hact);

  // layer 2 (mu & lv fused)
  proj2_kernel<<<(N_NODES + 63) / 64, 256, 0, stream>>>(hact, Wmu, Wlv, h2b);
  a2_kernel<<<N_NODES / 4, 256, 0, stream>>>(h2b, asmu, admu, aslv, adlv, a2);
  agg2_csr_kernel<<<N_NODES, 64, 0, stream>>>(
      counts, offs, csr, (const float4*)a2, h2b, bmu, blv, out);
}

// Round 7
// 238.225 us; speedup vs baseline: 4.1831x; 1.3090x over previous
//
#include <hip/hip_runtime.h>
#include <hip/hip_bf16.h>

#define N_NODES 50000
#define N_EDGES 800000
#define EP (N_EDGES + N_NODES)   // with self-loops
#define IN_C 128
#define HID 64
#define HEADS 2
#define LAT 32
#define NEG_SLOPE 0.2f
#define MAXDEG 256     // max in-degree; Poisson(17) -> P(>200) ~ 0
#define NBUCKET 391    // ceil(N_NODES/128): coarse dst-buckets of 128 nodes
#define BCAP 3072      // bucket capacity; expect ~2176 +- 47 (20 sigma margin)
#define CHUNK 4096     // edges per bucket_scatter block

typedef __attribute__((ext_vector_type(8))) short bf16x8;
typedef __attribute__((ext_vector_type(4))) float f32x4;

// fp32 -> bf16 round-to-nearest-even
__device__ __forceinline__ unsigned short f2bf(float f) {
  unsigned u = __float_as_uint(f);
  u += 0x7FFF + ((u >> 16) & 1);
  return (unsigned short)(u >> 16);
}
__device__ __forceinline__ float bf_lo(unsigned u) { return __uint_as_float(u << 16); }
__device__ __forceinline__ float bf_hi(unsigned u) { return __uint_as_float(u & 0xFFFF0000u); }

// load 8 contiguous fp32, convert to a bf16x8 A-fragment
__device__ __forceinline__ bf16x8 pack_bf8(const float* __restrict__ p) {
  float4 a = *(const float4*)p;
  float4 b = *(const float4*)(p + 4);
  bf16x8 r;
  r[0] = (short)f2bf(a.x); r[1] = (short)f2bf(a.y);
  r[2] = (short)f2bf(a.z); r[3] = (short)f2bf(a.w);
  r[4] = (short)f2bf(b.x); r[5] = (short)f2bf(b.y);
  r[6] = (short)f2bf(b.z); r[7] = (short)f2bf(b.w);
  return r;
}

// =================== bucketed CSR build (by dst) ============================
// cursor[b] starts at b*BCAP; buckets are fixed-capacity regions of csr.
__global__ void cursor_init_kernel(int* __restrict__ cursor) {
  int b = threadIdx.x;
  if (b < NBUCKET) cursor[b] = b * BCAP;
}

// Phase 1: bin edges into coarse buckets. LDS binning, per-(block,bucket)
// contiguous chunk writes (one global atomic per non-empty bucket per block)
// -> each csr cache line written by ~1 block instead of ~16 random XCDs.
__global__ __launch_bounds__(256) void bucket_scatter_kernel(
    const int* __restrict__ ei, int* __restrict__ cursor,
    unsigned* __restrict__ csr) {
  __shared__ int histL[512];           // bucket counts (padded to 512)
  __shared__ int baseL[512];           // exclusive prefix (staging layout)
  __shared__ int gbaseL[512];          // reserved global base per bucket
  __shared__ int wsumS[4];
  __shared__ int nvalS;
  __shared__ unsigned staging[CHUNK];
  __shared__ unsigned short bktidL[CHUNK];
  const int t = threadIdx.x, lane = t & 63, wid = t >> 6;
  for (int i = t; i < 512; i += 256) histL[i] = 0;
  __syncthreads();
  int myb[CHUNK / 256];
  int myloc[CHUNK / 256];
  unsigned mypay[CHUNK / 256];
  #pragma unroll
  for (int i = 0; i < CHUNK / 256; ++i) {
    int e = blockIdx.x * CHUNK + i * 256 + t;
    if (e < EP) {
      int s, d;
      if (e < N_EDGES) { s = ei[e]; d = ei[N_EDGES + e]; }
      else { s = d = e - N_EDGES; }
      int b = d >> 7;
      myb[i] = b;
      mypay[i] = ((unsigned)(d & 127) << 17) | (unsigned)s;  // s < 2^17
      myloc[i] = atomicAdd(&histL[b], 1);
    } else myb[i] = -1;
  }
  __syncthreads();
  // exclusive scan of histL[0..511]: 2 elems/thread + wave scan + wave offsets
  {
    int v0 = histL[2 * t], v1 = histL[2 * t + 1];
    int pair = v0 + v1, inc = pair;
    #pragma unroll
    for (int off = 1; off < 64; off <<= 1) {
      int nv = __shfl_up(inc, off);
      if (lane >= off) inc += nv;
    }
    if (lane == 63) wsumS[wid] = inc;
    __syncthreads();
    if (t == 0) {
      int run = 0;
      #pragma unroll
      for (int w = 0; w < 4; ++w) { int c = wsumS[w]; wsumS[w] = run; run += c; }
      nvalS = run;
    }
    __syncthreads();
    int excl = wsumS[wid] + inc - pair;
    baseL[2 * t] = excl;
    baseL[2 * t + 1] = excl + v0;
  }
  __syncthreads();
  #pragma unroll
  for (int i = 0; i < CHUNK / 256; ++i)
    if (myb[i] >= 0) {
      int p = baseL[myb[i]] + myloc[i];
      staging[p] = mypay[i];
      bktidL[p] = (unsigned short)myb[i];
    }
  // reserve global chunks (one atomic per non-empty bucket)
  for (int b = t; b < NBUCKET; b += 256) {
    int c = histL[b];
    gbaseL[b] = c ? atomicAdd(&cursor[b], c) : 0;
  }
  __syncthreads();
  const int nval = nvalS;
  for (int j = t; j < nval; j += 256) {
    int b = bktidL[j];
    int pos = gbaseL[b] + (j - baseL[b]);
    if (pos < (b + 1) * BCAP) csr[pos] = staging[j];   // overflow guard
  }
}

// Phase 2: one block per bucket. Per-node histogram + prefix in LDS, then
// in-place re-scatter (packed -> src-only, sorted by node). All writes land
// in a 12 KB window -> single-XCD, lines written once.
__global__ __launch_bounds__(256) void bucket_fill_kernel(
    const int* __restrict__ cursor, unsigned* __restrict__ csr,
    int* __restrict__ counts, int* __restrict__ cend) {
  __shared__ unsigned eseg[BCAP];
  __shared__ int hist[128];
  __shared__ int basef[128];
  __shared__ int cur[128];
  const int b = blockIdx.x, t = threadIdx.x;
  const int segbase = b * BCAP;
  int cnt = cursor[b] - segbase;
  if (cnt > BCAP) cnt = BCAP;
  if (t < 128) hist[t] = 0;
  __syncthreads();
  for (int j = t; j < cnt; j += 256) {
    unsigned u = csr[segbase + j];
    eseg[j] = u;
    atomicAdd(&hist[u >> 17], 1);
  }
  __syncthreads();
  if (t < 64) {   // exclusive scan of hist[0..127], single wave, 2 elems/lane
    int v0 = hist[2 * t], v1 = hist[2 * t + 1];
    int pair = v0 + v1, inc = pair;
    #pragma unroll
    for (int off = 1; off < 64; off <<= 1) {
      int nv = __shfl_up(inc, off);
      if (t >= off) inc += nv;
    }
    int excl = inc - pair;
    basef[2 * t] = excl;
    basef[2 * t + 1] = excl + v0;
  }
  __syncthreads();
  if (t < 128) {
    cur[t] = basef[t];
    int n = b * 128 + t;
    if (n < N_NODES) {
      counts[n] = hist[t];
      cend[n] = segbase + basef[t] + hist[t];
    }
  }
  __syncthreads();
  for (int j = t; j < cnt; j += 256) {
    unsigned u = eseg[j];
    int dl = u >> 17;
    int p = atomicAdd(&cur[dl], 1);
    csr[segbase + p] = u & 0x1FFFF;    // src id only
  }
}

// ------------- proj1 (MFMA): h1b(bf16) = x @ W1  (50000x128 @ 128x128) ------
__global__ __launch_bounds__(256) void proj1_kernel(
    const float* __restrict__ x, const float* __restrict__ W,
    unsigned short* __restrict__ h1b) {
  __shared__ unsigned short Wb[16384];   // 32 KB, B-frag layout
  const int t = threadIdx.x;
  for (int i = t; i < 128 * 128; i += 256) {
    int k = i >> 7, n = i & 127;
    int kk = k >> 5, q = (k >> 3) & 3, j = k & 7;
    Wb[((((kk << 2) + q) << 7) + n) * 8 + j] = f2bf(W[i]);
  }
  __syncthreads();
  const int w = t >> 6, lane = t & 63;
  const int m = lane & 15, quad = lane >> 4;
  const int row0 = blockIdx.x * 32;
  const int n0 = w * 32;
  f32x4 acc[2][2] = {};
  #pragma unroll
  for (int kk = 0; kk < 4; ++kk) {
    bf16x8 afr[2], bfr[2];
    #pragma unroll
    for (int mt = 0; mt < 2; ++mt) {
      int row = row0 + mt * 16 + m;
      if (row >= N_NODES) row = N_NODES - 1;
      afr[mt] = pack_bf8(x + (size_t)row * 128 + kk * 32 + quad * 8);
    }
    #pragma unroll
    for (int nt = 0; nt < 2; ++nt)
      bfr[nt] = *(const bf16x8*)&Wb[((((kk << 2) + quad) << 7) + n0 + nt * 16 + m) * 8];
    #pragma unroll
    for (int mt = 0; mt < 2; ++mt)
      #pragma unroll
      for (int nt = 0; nt < 2; ++nt)
        acc[mt][nt] = __builtin_amdgcn_mfma_f32_16x16x32_bf16(
            afr[mt], bfr[nt], acc[mt][nt], 0, 0, 0);
  }
  #pragma unroll
  for (int mt = 0; mt < 2; ++mt)
    #pragma unroll
    for (int r = 0; r < 4; ++r) {
      int row = row0 + mt * 16 + quad * 4 + r;
      if (row < N_NODES) {
        #pragma unroll
        for (int nt = 0; nt < 2; ++nt)
          h1b[(size_t)row * 128 + n0 + nt * 16 + m] = f2bf(acc[mt][nt][r]);
      }
    }
}

// --------- a1 pass: a1[n] = (as_h0, as_h1, ad_h0, ad_h1) from bf16 h1 -------
__global__ __launch_bounds__(256) void a1_kernel(
    const unsigned* __restrict__ h1b2, const float* __restrict__ att_src,
    const float* __restrict__ att_dst, float* __restrict__ a1) {
  const int n = blockIdx.x * 4 + (threadIdx.x >> 6);
  const int lane = threadIdx.x & 63;
  unsigned u = h1b2[(size_t)n * 64 + lane];
  float h0 = bf_lo(u), h1v = bf_hi(u);
  int head = lane >> 5;
  int cc = (lane * 2) & 63;
  float s = h0 * att_src[head * HID + cc] + h1v * att_src[head * HID + cc + 1];
  float d = h0 * att_dst[head * HID + cc] + h1v * att_dst[head * HID + cc + 1];
  #pragma unroll
  for (int off = 16; off; off >>= 1) {
    s += __shfl_xor(s, off);
    d += __shfl_xor(d, off);
  }
  if ((lane & 31) == 0) {
    a1[n * 4 + head] = s;
    a1[n * 4 + 2 + head] = d;
  }
}

// ---- layer-1 gather-aggregate: weights once per edge (LDS), bf16 gather ----
__global__ __launch_bounds__(64) void agg1_csr_kernel(
    const int* __restrict__ counts, const int* __restrict__ cend,
    const unsigned* __restrict__ csr_src, const float4* __restrict__ a1,
    const unsigned* __restrict__ h1b2, const float* __restrict__ b,
    float* __restrict__ hact) {
  __shared__ float w_lds[2][MAXDEG];
  __shared__ int   s_lds[MAXDEG];
  const int n = blockIdx.x;
  const int t = threadIdx.x;
  const int end = cend[n];
  int cnt = counts[n];
  if (cnt > MAXDEG) cnt = MAXDEG;
  const int beg = end - cnt;
  const float4 bv = a1[n];
  float p0 = 0.f, p1 = 0.f;
  for (int i = t; i < cnt; i += 64) {
    int s = (int)csr_src[beg + i];
    float4 av = a1[s];
    float l0 = av.x + bv.z; l0 = l0 > 0.f ? l0 : NEG_SLOPE * l0;
    float l1 = av.y + bv.w; l1 = l1 > 0.f ? l1 : NEG_SLOPE * l1;
    float e0 = expf(l0), e1 = expf(l1);
    w_lds[0][i] = e0; w_lds[1][i] = e1; s_lds[i] = s;
    p0 += e0; p1 += e1;
  }
  #pragma unroll
  for (int off = 32; off; off >>= 1) {
    p0 += __shfl_xor(p0, off);
    p1 += __shfl_xor(p1, off);
  }
  __syncthreads();
  const int head = t >> 5;
  const unsigned* hp = h1b2 + t;
  float ax = 0.f, ay = 0.f;
  #pragma unroll 4
  for (int i = 0; i < cnt; ++i) {
    int s = s_lds[i];
    float w = w_lds[head][i];
    unsigned u = hp[(size_t)s * 64];
    ax += bf_lo(u) * w; ay += bf_hi(u) * w;
  }
  float inv = 1.f / ((head ? p1 : p0) + 1e-16f);
  float vx = ax * inv + b[t * 2];
  float vy = ay * inv + b[t * 2 + 1];
  vx = vx > 0.f ? vx : (expf(vx) - 1.f);
  vy = vy > 0.f ? vy : (expf(vy) - 1.f);
  *(float2*)(hact + (size_t)n * 128 + t * 2) = make_float2(vx, vy);
}

// ------- proj2 (MFMA): h2b(bf16) = hact @ [Wmu|Wlv]  (50000x128 @ 128x64) ---
__global__ __launch_bounds__(256) void proj2_kernel(
    const float* __restrict__ h, const float* __restrict__ Wmu,
    const float* __restrict__ Wlv, unsigned short* __restrict__ h2b) {
  __shared__ unsigned short Wb[8192];   // 16 KB
  const int t = threadIdx.x;
  for (int i = t; i < 128 * 64; i += 256) {
    int k = i >> 6, n = i & 63;
    float v = (n < 32) ? Wmu[k * 32 + n] : Wlv[k * 32 + (n - 32)];
    int kk = k >> 5, q = (k >> 3) & 3, j = k & 7;
    Wb[((((kk << 2) + q) << 6) + n) * 8 + j] = f2bf(v);
  }
  __syncthreads();
  const int w = t >> 6, lane = t & 63;
  const int m = lane & 15, quad = lane >> 4;
  const int row0 = blockIdx.x * 64 + (w >> 1) * 32;
  const int n0 = (w & 1) * 32;
  f32x4 acc[2][2] = {};
  #pragma unroll
  for (int kk = 0; kk < 4; ++kk) {
    bf16x8 afr[2], bfr[2];
    #pragma unroll
    for (int mt = 0; mt < 2; ++mt) {
      int row = row0 + mt * 16 + m;
      if (row >= N_NODES) row = N_NODES - 1;
      afr[mt] = pack_bf8(h + (size_t)row * 128 + kk * 32 + quad * 8);
    }
    #pragma unroll
    for (int nt = 0; nt < 2; ++nt)
      bfr[nt] = *(const bf16x8*)&Wb[((((kk << 2) + quad) << 6) + n0 + nt * 16 + m) * 8];
    #pragma unroll
    for (int mt = 0; mt < 2; ++mt)
      #pragma unroll
      for (int nt = 0; nt < 2; ++nt)
        acc[mt][nt] = __builtin_amdgcn_mfma_f32_16x16x32_bf16(
            afr[mt], bfr[nt], acc[mt][nt], 0, 0, 0);
  }
  #pragma unroll
  for (int mt = 0; mt < 2; ++mt)
    #pragma unroll
    for (int r = 0; r < 4; ++r) {
      int row = row0 + mt * 16 + quad * 4 + r;
      if (row < N_NODES) {
        #pragma unroll
        for (int nt = 0; nt < 2; ++nt)
          h2b[(size_t)row * 64 + n0 + nt * 16 + m] = f2bf(acc[mt][nt][r]);
      }
    }
}

// --------- a2 pass: a2[n] = (as_mu, ad_mu, as_lv, ad_lv) from bf16 h2 -------
__global__ __launch_bounds__(256) void a2_kernel(
    const unsigned short* __restrict__ h2b, const float* __restrict__ asmu,
    const float* __restrict__ admu, const float* __restrict__ aslv,
    const float* __restrict__ adlv, float* __restrict__ a2) {
  const int n = blockIdx.x * 4 + (threadIdx.x >> 6);
  const int lane = threadIdx.x & 63;
  float h = __uint_as_float(((unsigned)h2b[(size_t)n * 64 + lane]) << 16);
  int j = lane >> 5, o = lane & 31;
  float s = h * (j ? aslv : asmu)[o];
  float d = h * (j ? adlv : admu)[o];
  #pragma unroll
  for (int off = 16; off; off >>= 1) {
    s += __shfl_xor(s, off);
    d += __shfl_xor(d, off);
  }
  if (o == 0) {
    a2[n * 4 + j * 2 + 0] = s;
    a2[n * 4 + j * 2 + 1] = d;
  }
}

// ---- layer-2 gather-aggregate -> out (+bias) -------------------------------
__global__ __launch_bounds__(64) void agg2_csr_kernel(
    const int* __restrict__ counts, const int* __restrict__ cend,
    const unsigned* __restrict__ csr_src, const float4* __restrict__ a2,
    const unsigned short* __restrict__ h2b,
    const float* __restrict__ bmu, const float* __restrict__ blv,
    float* __restrict__ out) {
  __shared__ float w_lds[2][MAXDEG];
  __shared__ int   s_lds[MAXDEG];
  const int n = blockIdx.x;
  const int t = threadIdx.x;
  const int end = cend[n];
  int cnt = counts[n];
  if (cnt > MAXDEG) cnt = MAXDEG;
  const int beg = end - cnt;
  const float4 bv = a2[n];
  float p0 = 0.f, p1 = 0.f;
  for (int i = t; i < cnt; i += 64) {
    int s = (int)csr_src[beg + i];
    float4 av = a2[s];
    float l0 = av.x + bv.y; l0 = l0 > 0.f ? l0 : NEG_SLOPE * l0;  // mu
    float l1 = av.z + bv.w; l1 = l1 > 0.f ? l1 : NEG_SLOPE * l1;  // lv
    float e0 = expf(l0), e1 = expf(l1);
    w_lds[0][i] = e0; w_lds[1][i] = e1; s_lds[i] = s;
    p0 += e0; p1 += e1;
  }
  #pragma unroll
  for (int off = 32; off; off >>= 1) {
    p0 += __shfl_xor(p0, off);
    p1 += __shfl_xor(p1, off);
  }
  __syncthreads();
  const int j = t >> 5, o = t & 31;
  const unsigned short* hp = h2b + t;
  float acc = 0.f;
  #pragma unroll 4
  for (int i = 0; i < cnt; ++i) {
    int s = s_lds[i];
    float hv = __uint_as_float(((unsigned)hp[(size_t)s * 64]) << 16);
    acc += hv * w_lds[j][i];
  }
  float inv = 1.f / ((j ? p1 : p0) + 1e-16f);
  out[(size_t)j * N_NODES * LAT + (size_t)n * LAT + o] =
      acc * inv + (j ? blv : bmu)[o];
}

extern "C" void kernel_launch(void* const* d_in, const int* in_sizes, int n_in,
                              void* d_out, int out_size, void* d_ws, size_t ws_size,
                              hipStream_t stream) {
  const float* x        = (const float*)d_in[0];
  const int* ei         = (const int*)d_in[1];   // int32 per harness contract
  const float* W1       = (const float*)d_in[2];
  const float* att_src1 = (const float*)d_in[3];
  const float* att_dst1 = (const float*)d_in[4];
  const float* b1       = (const float*)d_in[5];
  const float* Wmu      = (const float*)d_in[6];
  const float* asmu     = (const float*)d_in[7];
  const float* admu     = (const float*)d_in[8];
  const float* bmu      = (const float*)d_in[9];
  const float* Wlv      = (const float*)d_in[10];
  const float* aslv     = (const float*)d_in[11];
  const float* adlv     = (const float*)d_in[12];
  const float* blv      = (const float*)d_in[13];
  float* out = (float*)d_out;

  // workspace layout (4-B units):
  //  [hact N*128 | a1 N*4 | a2 N*4 | h1b N*64(bf16 pairs) | h2b N*32 |
  //   counts N | cend N | cursor NBUCKET | csr NBUCKET*BCAP]
  float* ws   = (float*)d_ws;
  float* hact = ws;
  float* a1   = hact + (size_t)N_NODES * 128;
  float* a2   = a1 + (size_t)N_NODES * 4;
  unsigned short* h1b = (unsigned short*)(a2 + (size_t)N_NODES * 4);
  unsigned short* h2b = h1b + (size_t)N_NODES * 128;
  int* counts = (int*)(h2b + (size_t)N_NODES * 64);
  int* cend   = counts + N_NODES;
  int* cursor = cend + N_NODES;
  unsigned* csr = (unsigned*)(cursor + NBUCKET);

  // CSR build (no memsets needed; every consumed byte is written)
  cursor_init_kernel<<<1, 512, 0, stream>>>(cursor);
  bucket_scatter_kernel<<<(EP + CHUNK - 1) / CHUNK, 256, 0, stream>>>(ei, cursor, csr);
  bucket_fill_kernel<<<NBUCKET, 256, 0, stream>>>(cursor, csr, counts, cend);

  // layer 1
  proj1_kernel<<<(N_NODES + 31) / 32, 256, 0, stream>>>(x, W1, h1b);
  a1_kernel<<<N_NODES / 4, 256, 0, stream>>>(
      (const unsigned*)h1b, att_src1, att_dst1, a1);
  agg1_csr_kernel<<<N_NODES, 64, 0, stream>>>(
      counts, cend, csr, (const float4*)a1, (const unsigned*)h1b, b1, hact);

  // layer 2 (mu & lv fused)
  proj2_kernel<<<(N_NODES + 63) / 64, 256, 0, stream>>>(hact, Wmu, Wlv, h2b);
  a2_kernel<<<N_NODES / 4, 256, 0, stream>>>(h2b, asmu, admu, aslv, adlv, a2);
  agg2_csr_kernel<<<N_NODES, 64, 0, stream>>>(
      counts, cend, csr, (const float4*)a2, h2b, bmu, blv, out);
}

// Round 8
// 220.153 us; speedup vs baseline: 4.5265x; 1.0821x over previous
//
#include <hip/hip_runtime.h>
#include <hip/hip_bf16.h>

#define N_NODES 50000
#define N_EDGES 800000
#define EP (N_EDGES + N_NODES)   // with self-loops
#define IN_C 128
#define HID 64
#define HEADS 2
#define LAT 32
#define NEG_SLOPE 0.2f
#define MAXDEG 256     // max in-degree; Poisson(17) -> P(>200) ~ 0
#define NBUCKET 391    // ceil(N_NODES/128): coarse dst-buckets of 128 nodes
#define BCAP 3072      // bucket capacity; expect ~2176 +- 47 (20 sigma margin)
#define CHUNK 4096     // edges per bucket_scatter block
#define NSCAT ((EP + CHUNK - 1) / CHUNK)   // 208 scatter blocks
#define NPROJ1 ((N_NODES + 31) / 32)       // 1563 proj1 blocks

typedef __attribute__((ext_vector_type(8))) short bf16x8;
typedef __attribute__((ext_vector_type(4))) float f32x4;

// fp32 -> bf16 round-to-nearest-even
__device__ __forceinline__ unsigned short f2bf(float f) {
  unsigned u = __float_as_uint(f);
  u += 0x7FFF + ((u >> 16) & 1);
  return (unsigned short)(u >> 16);
}
__device__ __forceinline__ float bf_lo(unsigned u) { return __uint_as_float(u << 16); }
__device__ __forceinline__ float bf_hi(unsigned u) { return __uint_as_float(u & 0xFFFF0000u); }

__device__ __forceinline__ bf16x8 pack_bf8(const float* __restrict__ p) {
  float4 a = *(const float4*)p;
  float4 b = *(const float4*)(p + 4);
  bf16x8 r;
  r[0] = (short)f2bf(a.x); r[1] = (short)f2bf(a.y);
  r[2] = (short)f2bf(a.z); r[3] = (short)f2bf(a.w);
  r[4] = (short)f2bf(b.x); r[5] = (short)f2bf(b.y);
  r[6] = (short)f2bf(b.z); r[7] = (short)f2bf(b.w);
  return r;
}

// ---------------- K1 shared-memory overlay (scatter | proj1) ----------------
struct ScatSmem {
  int histL[512];
  int baseL[512];
  int gbaseL[512];
  int wsumS[4];
  int nvalS;
  unsigned staging[CHUNK];
  unsigned short bktidL[CHUNK];
};
struct Proj1Smem {
  unsigned short Wb[16384];   // 32 KB, B-frag layout
  float part[32][4];          // a1 partials: (s_h0, s_h1, d_h0, d_h1)
};
union K1Smem { ScatSmem sc; Proj1Smem pj; };

// ================= K1: bucket_scatter (blocks 0..NSCAT) =====================
// =================     proj1 + fused a1 (blocks NSCAT..) ====================
__global__ __launch_bounds__(256) void k1_kernel(
    const int* __restrict__ ei, int* __restrict__ cursor,
    unsigned* __restrict__ csr,
    const float* __restrict__ x, const float* __restrict__ W,
    const float* __restrict__ att_src, const float* __restrict__ att_dst,
    unsigned short* __restrict__ h1b, float* __restrict__ a1) {
  __shared__ K1Smem sm;
  const int t = threadIdx.x, lane = t & 63, wid = t >> 6;

  if (blockIdx.x < NSCAT) {
    // ---------------- bucket scatter: LDS binning, chunked global writes ----
    for (int i = t; i < 512; i += 256) sm.sc.histL[i] = 0;
    __syncthreads();
    int myb[CHUNK / 256];
    int myloc[CHUNK / 256];
    unsigned mypay[CHUNK / 256];
    #pragma unroll
    for (int i = 0; i < CHUNK / 256; ++i) {
      int e = blockIdx.x * CHUNK + i * 256 + t;
      if (e < EP) {
        int s, d;
        if (e < N_EDGES) { s = ei[e]; d = ei[N_EDGES + e]; }
        else { s = d = e - N_EDGES; }
        int b = d >> 7;
        myb[i] = b;
        mypay[i] = ((unsigned)(d & 127) << 17) | (unsigned)s;  // s < 2^17
        myloc[i] = atomicAdd(&sm.sc.histL[b], 1);
      } else myb[i] = -1;
    }
    __syncthreads();
    {   // exclusive scan of histL[0..511]
      int v0 = sm.sc.histL[2 * t], v1 = sm.sc.histL[2 * t + 1];
      int pair = v0 + v1, inc = pair;
      #pragma unroll
      for (int off = 1; off < 64; off <<= 1) {
        int nv = __shfl_up(inc, off);
        if (lane >= off) inc += nv;
      }
      if (lane == 63) sm.sc.wsumS[wid] = inc;
      __syncthreads();
      if (t == 0) {
        int run = 0;
        #pragma unroll
        for (int w = 0; w < 4; ++w) { int c = sm.sc.wsumS[w]; sm.sc.wsumS[w] = run; run += c; }
        sm.sc.nvalS = run;
      }
      __syncthreads();
      int excl = sm.sc.wsumS[wid] + inc - pair;
      sm.sc.baseL[2 * t] = excl;
      sm.sc.baseL[2 * t + 1] = excl + v0;
    }
    __syncthreads();
    #pragma unroll
    for (int i = 0; i < CHUNK / 256; ++i)
      if (myb[i] >= 0) {
        int p = sm.sc.baseL[myb[i]] + myloc[i];
        sm.sc.staging[p] = mypay[i];
        sm.sc.bktidL[p] = (unsigned short)myb[i];
      }
    for (int b = t; b < NBUCKET; b += 256) {   // reserve chunks (relative)
      int c = sm.sc.histL[b];
      sm.sc.gbaseL[b] = c ? atomicAdd(&cursor[b], c) : 0;
    }
    __syncthreads();
    const int nval = sm.sc.nvalS;
    for (int j = t; j < nval; j += 256) {
      int b = sm.sc.bktidL[j];
      int off = sm.sc.gbaseL[b] + (j - sm.sc.baseL[b]);
      if (off < BCAP) csr[b * BCAP + off] = sm.sc.staging[j];  // overflow guard
    }
  } else {
    // ---------------- proj1 (MFMA) + fused a1 epilogue ----------------------
    const int pb = blockIdx.x - NSCAT;        // 0..NPROJ1-1
    for (int i = t; i < 128 * 128; i += 256) {
      int k = i >> 7, n = i & 127;
      int kk = k >> 5, q = (k >> 3) & 3, j = k & 7;
      sm.pj.Wb[((((kk << 2) + q) << 7) + n) * 8 + j] = f2bf(W[i]);
    }
    if (t < 128) ((float*)sm.pj.part)[t] = 0.f;
    __syncthreads();
    const int w = wid;
    const int m = lane & 15, quad = lane >> 4;
    const int row0 = pb * 32;
    const int n0 = w * 32;
    const int head = w >> 1;                  // cols n0.. all in one head
    f32x4 acc[2][2] = {};
    #pragma unroll
    for (int kk = 0; kk < 4; ++kk) {
      bf16x8 afr[2], bfr[2];
      #pragma unroll
      for (int mt = 0; mt < 2; ++mt) {
        int row = row0 + mt * 16 + m;
        if (row >= N_NODES) row = N_NODES - 1;
        afr[mt] = pack_bf8(x + (size_t)row * 128 + kk * 32 + quad * 8);
      }
      #pragma unroll
      for (int nt = 0; nt < 2; ++nt)
        bfr[nt] = *(const bf16x8*)&sm.pj.Wb[((((kk << 2) + quad) << 7) + n0 + nt * 16 + m) * 8];
      #pragma unroll
      for (int mt = 0; mt < 2; ++mt)
        #pragma unroll
        for (int nt = 0; nt < 2; ++nt)
          acc[mt][nt] = __builtin_amdgcn_mfma_f32_16x16x32_bf16(
              afr[mt], bfr[nt], acc[mt][nt], 0, 0, 0);
    }
    // per-lane att values for this wave's two 16-col groups (within head)
    float asv[2], adv[2];
    #pragma unroll
    for (int nt = 0; nt < 2; ++nt) {
      int cc = ((n0 & 63) + nt * 16 + m);
      asv[nt] = att_src[head * HID + cc];
      adv[nt] = att_dst[head * HID + cc];
    }
    #pragma unroll
    for (int mt = 0; mt < 2; ++mt)
      #pragma unroll
      for (int r = 0; r < 4; ++r) {
        int row = row0 + mt * 16 + quad * 4 + r;
        if (row < N_NODES) {
          #pragma unroll
          for (int nt = 0; nt < 2; ++nt)
            h1b[(size_t)row * 128 + n0 + nt * 16 + m] = f2bf(acc[mt][nt][r]);
        }
        float s = acc[mt][0][r] * asv[0] + acc[mt][1][r] * asv[1];
        float d = acc[mt][0][r] * adv[0] + acc[mt][1][r] * adv[1];
        #pragma unroll
        for (int off = 8; off; off >>= 1) {   // reduce 16 col-lanes (in-quad)
          s += __shfl_xor(s, off);
          d += __shfl_xor(d, off);
        }
        if (m == 0) {   // two waves per head accumulate
          atomicAdd(&sm.pj.part[mt * 16 + quad * 4 + r][head], s);
          atomicAdd(&sm.pj.part[mt * 16 + quad * 4 + r][2 + head], d);
        }
      }
    __syncthreads();
    if (t < 32) {
      int row = row0 + t;
      if (row < N_NODES)
        *(float4*)&a1[(size_t)row * 4] = make_float4(
            sm.pj.part[t][0], sm.pj.part[t][1], sm.pj.part[t][2], sm.pj.part[t][3]);
    }
  }
}

// Phase 2: one block per bucket; per-node histogram + prefix + in-place
// re-scatter within an L2-local 12 KB window.
__global__ __launch_bounds__(256) void bucket_fill_kernel(
    const int* __restrict__ cursor, unsigned* __restrict__ csr,
    int* __restrict__ counts, int* __restrict__ cend) {
  __shared__ unsigned eseg[BCAP];
  __shared__ int hist[128];
  __shared__ int basef[128];
  __shared__ int cur[128];
  const int b = blockIdx.x, t = threadIdx.x;
  const int segbase = b * BCAP;
  int cnt = cursor[b];
  if (cnt > BCAP) cnt = BCAP;
  if (t < 128) hist[t] = 0;
  __syncthreads();
  for (int j = t; j < cnt; j += 256) {
    unsigned u = csr[segbase + j];
    eseg[j] = u;
    atomicAdd(&hist[u >> 17], 1);
  }
  __syncthreads();
  if (t < 64) {   // exclusive scan of hist[0..127]
    int v0 = hist[2 * t], v1 = hist[2 * t + 1];
    int pair = v0 + v1, inc = pair;
    #pragma unroll
    for (int off = 1; off < 64; off <<= 1) {
      int nv = __shfl_up(inc, off);
      if (t >= off) inc += nv;
    }
    int excl = inc - pair;
    basef[2 * t] = excl;
    basef[2 * t + 1] = excl + v0;
  }
  __syncthreads();
  if (t < 128) {
    cur[t] = basef[t];
    int n = b * 128 + t;
    if (n < N_NODES) {
      counts[n] = hist[t];
      cend[n] = segbase + basef[t] + hist[t];
    }
  }
  __syncthreads();
  for (int j = t; j < cnt; j += 256) {
    unsigned u = eseg[j];
    int dl = u >> 17;
    int p = atomicAdd(&cur[dl], 1);
    csr[segbase + p] = u & 0x1FFFF;    // src id only
  }
}

// ---- layer-1 gather-aggregate: weights once per edge (LDS), bf16 gather ----
__global__ __launch_bounds__(64) void agg1_csr_kernel(
    const int* __restrict__ counts, const int* __restrict__ cend,
    const unsigned* __restrict__ csr_src, const float4* __restrict__ a1,
    const unsigned* __restrict__ h1b2, const float* __restrict__ b,
    float* __restrict__ hact) {
  __shared__ float w_lds[2][MAXDEG];
  __shared__ int   s_lds[MAXDEG];
  const int n = blockIdx.x;
  const int t = threadIdx.x;
  const int end = cend[n];
  int cnt = counts[n];
  if (cnt > MAXDEG) cnt = MAXDEG;
  const int beg = end - cnt;
  const float4 bv = a1[n];
  float p0 = 0.f, p1 = 0.f;
  for (int i = t; i < cnt; i += 64) {
    int s = (int)csr_src[beg + i];
    float4 av = a1[s];
    float l0 = av.x + bv.z; l0 = l0 > 0.f ? l0 : NEG_SLOPE * l0;
    float l1 = av.y + bv.w; l1 = l1 > 0.f ? l1 : NEG_SLOPE * l1;
    float e0 = expf(l0), e1 = expf(l1);
    w_lds[0][i] = e0; w_lds[1][i] = e1; s_lds[i] = s;
    p0 += e0; p1 += e1;
  }
  #pragma unroll
  for (int off = 32; off; off >>= 1) {
    p0 += __shfl_xor(p0, off);
    p1 += __shfl_xor(p1, off);
  }
  __syncthreads();
  const int head = t >> 5;
  const unsigned* hp = h1b2 + t;
  float ax = 0.f, ay = 0.f;
  #pragma unroll 4
  for (int i = 0; i < cnt; ++i) {
    int s = s_lds[i];
    float w = w_lds[head][i];
    unsigned u = hp[(size_t)s * 64];
    ax += bf_lo(u) * w; ay += bf_hi(u) * w;
  }
  float inv = 1.f / ((head ? p1 : p0) + 1e-16f);
  float vx = ax * inv + b[t * 2];
  float vy = ay * inv + b[t * 2 + 1];
  vx = vx > 0.f ? vx : (expf(vx) - 1.f);
  vy = vy > 0.f ? vy : (expf(vy) - 1.f);
  *(float2*)(hact + (size_t)n * 128 + t * 2) = make_float2(vx, vy);
}

// ------- proj2 (MFMA) + fused a2: h2b = hact @ [Wmu|Wlv], a2 scalars --------
__global__ __launch_bounds__(256) void proj2_kernel(
    const float* __restrict__ h, const float* __restrict__ Wmu,
    const float* __restrict__ Wlv,
    const float* __restrict__ asmu, const float* __restrict__ admu,
    const float* __restrict__ aslv, const float* __restrict__ adlv,
    unsigned short* __restrict__ h2b, float* __restrict__ a2) {
  __shared__ unsigned short Wb[8192];   // 16 KB
  const int t = threadIdx.x;
  for (int i = t; i < 128 * 64; i += 256) {
    int k = i >> 6, n = i & 63;
    float v = (n < 32) ? Wmu[k * 32 + n] : Wlv[k * 32 + (n - 32)];
    int kk = k >> 5, q = (k >> 3) & 3, j = k & 7;
    Wb[((((kk << 2) + q) << 6) + n) * 8 + j] = f2bf(v);
  }
  __syncthreads();
  const int w = t >> 6, lane = t & 63;
  const int m = lane & 15, quad = lane >> 4;
  const int row0 = blockIdx.x * 64 + (w >> 1) * 32;
  const int j = w & 1;                 // 0 = mu, 1 = lv
  const int n0 = j * 32;
  f32x4 acc[2][2] = {};
  #pragma unroll
  for (int kk = 0; kk < 4; ++kk) {
    bf16x8 afr[2], bfr[2];
    #pragma unroll
    for (int mt = 0; mt < 2; ++mt) {
      int row = row0 + mt * 16 + m;
      if (row >= N_NODES) row = N_NODES - 1;
      afr[mt] = pack_bf8(h + (size_t)row * 128 + kk * 32 + quad * 8);
    }
    #pragma unroll
    for (int nt = 0; nt < 2; ++nt)
      bfr[nt] = *(const bf16x8*)&Wb[((((kk << 2) + quad) << 6) + n0 + nt * 16 + m) * 8];
    #pragma unroll
    for (int mt = 0; mt < 2; ++mt)
      #pragma unroll
      for (int nt = 0; nt < 2; ++nt)
        acc[mt][nt] = __builtin_amdgcn_mfma_f32_16x16x32_bf16(
            afr[mt], bfr[nt], acc[mt][nt], 0, 0, 0);
  }
  // per-lane att values (each wave covers the full 32 cols of its j)
  float asv[2], adv[2];
  #pragma unroll
  for (int nt = 0; nt < 2; ++nt) {
    int o = nt * 16 + m;
    asv[nt] = (j ? aslv : asmu)[o];
    adv[nt] = (j ? adlv : admu)[o];
  }
  #pragma unroll
  for (int mt = 0; mt < 2; ++mt)
    #pragma unroll
    for (int r = 0; r < 4; ++r) {
      int row = row0 + mt * 16 + quad * 4 + r;
      if (row < N_NODES) {
        #pragma unroll
        for (int nt = 0; nt < 2; ++nt)
          h2b[(size_t)row * 64 + n0 + nt * 16 + m] = f2bf(acc[mt][nt][r]);
      }
      float s = acc[mt][0][r] * asv[0] + acc[mt][1][r] * asv[1];
      float d = acc[mt][0][r] * adv[0] + acc[mt][1][r] * adv[1];
      #pragma unroll
      for (int off = 8; off; off >>= 1) {   // reduce 16 col-lanes
        s += __shfl_xor(s, off);
        d += __shfl_xor(d, off);
      }
      if (m == 0 && row < N_NODES) {
        a2[(size_t)row * 4 + j * 2 + 0] = s;   // (s_mu, d_mu, s_lv, d_lv)
        a2[(size_t)row * 4 + j * 2 + 1] = d;
      }
    }
}

// ---- layer-2 gather-aggregate -> out (+bias) -------------------------------
__global__ __launch_bounds__(64) void agg2_csr_kernel(
    const int* __restrict__ counts, const int* __restrict__ cend,
    const unsigned* __restrict__ csr_src, const float4* __restrict__ a2,
    const unsigned short* __restrict__ h2b,
    const float* __restrict__ bmu, const float* __restrict__ blv,
    float* __restrict__ out) {
  __shared__ float w_lds[2][MAXDEG];
  __shared__ int   s_lds[MAXDEG];
  const int n = blockIdx.x;
  const int t = threadIdx.x;
  const int end = cend[n];
  int cnt = counts[n];
  if (cnt > MAXDEG) cnt = MAXDEG;
  const int beg = end - cnt;
  const float4 bv = a2[n];
  float p0 = 0.f, p1 = 0.f;
  for (int i = t; i < cnt; i += 64) {
    int s = (int)csr_src[beg + i];
    float4 av = a2[s];
    float l0 = av.x + bv.y; l0 = l0 > 0.f ? l0 : NEG_SLOPE * l0;  // mu
    float l1 = av.z + bv.w; l1 = l1 > 0.f ? l1 : NEG_SLOPE * l1;  // lv
    float e0 = expf(l0), e1 = expf(l1);
    w_lds[0][i] = e0; w_lds[1][i] = e1; s_lds[i] = s;
    p0 += e0; p1 += e1;
  }
  #pragma unroll
  for (int off = 32; off; off >>= 1) {
    p0 += __shfl_xor(p0, off);
    p1 += __shfl_xor(p1, off);
  }
  __syncthreads();
  const int j = t >> 5, o = t & 31;
  const unsigned short* hp = h2b + t;
  float acc = 0.f;
  #pragma unroll 4
  for (int i = 0; i < cnt; ++i) {
    int s = s_lds[i];
    float hv = __uint_as_float(((unsigned)hp[(size_t)s * 64]) << 16);
    acc += hv * w_lds[j][i];
  }
  float inv = 1.f / ((j ? p1 : p0) + 1e-16f);
  out[(size_t)j * N_NODES * LAT + (size_t)n * LAT + o] =
      acc * inv + (j ? blv : bmu)[o];
}

extern "C" void kernel_launch(void* const* d_in, const int* in_sizes, int n_in,
                              void* d_out, int out_size, void* d_ws, size_t ws_size,
                              hipStream_t stream) {
  const float* x        = (const float*)d_in[0];
  const int* ei         = (const int*)d_in[1];   // int32 per harness contract
  const float* W1       = (const float*)d_in[2];
  const float* att_src1 = (const float*)d_in[3];
  const float* att_dst1 = (const float*)d_in[4];
  const float* b1       = (const float*)d_in[5];
  const float* Wmu      = (const float*)d_in[6];
  const float* asmu     = (const float*)d_in[7];
  const float* admu     = (const float*)d_in[8];
  const float* bmu      = (const float*)d_in[9];
  const float* Wlv      = (const float*)d_in[10];
  const float* aslv     = (const float*)d_in[11];
  const float* adlv     = (const float*)d_in[12];
  const float* blv      = (const float*)d_in[13];
  float* out = (float*)d_out;

  // workspace layout (4-B units):
  //  [hact N*128 | a1 N*4 | a2 N*4 | h1b N*64(bf16 pairs) | h2b N*32 |
  //   counts N | cend N | cursor NBUCKET | csr NBUCKET*BCAP]
  float* ws   = (float*)d_ws;
  float* hact = ws;
  float* a1   = hact + (size_t)N_NODES * 128;
  float* a2   = a1 + (size_t)N_NODES * 4;
  unsigned short* h1b = (unsigned short*)(a2 + (size_t)N_NODES * 4);
  unsigned short* h2b = h1b + (size_t)N_NODES * 128;
  int* counts = (int*)(h2b + (size_t)N_NODES * 64);
  int* cend   = counts + N_NODES;
  int* cursor = cend + N_NODES;
  unsigned* csr = (unsigned*)(cursor + NBUCKET);

  // cursors are bucket-relative now: plain zero init
  hipMemsetAsync(cursor, 0, NBUCKET * sizeof(int), stream);

  // K1: bucket_scatter (208 blocks) || proj1+a1 (1563 blocks)
  k1_kernel<<<NSCAT + NPROJ1, 256, 0, stream>>>(
      ei, cursor, csr, x, W1, att_src1, att_dst1, h1b, a1);
  bucket_fill_kernel<<<NBUCKET, 256, 0, stream>>>(cursor, csr, counts, cend);
  agg1_csr_kernel<<<N_NODES, 64, 0, stream>>>(
      counts, cend, csr, (const float4*)a1, (const unsigned*)h1b, b1, hact);
  proj2_kernel<<<(N_NODES + 63) / 64, 256, 0, stream>>>(
      hact, Wmu, Wlv, asmu, admu, aslv, adlv, h2b, a2);
  agg2_csr_kernel<<<N_NODES, 64, 0, stream>>>(
      counts, cend, csr, (const float4*)a2, h2b, bmu, blv, out);
}

// Round 10
// 209.590 us; speedup vs baseline: 4.7546x; 1.0504x over previous
//
#include <hip/hip_runtime.h>
#include <hip/hip_bf16.h>

#define N_NODES 50000
#define N_EDGES 800000
#define EP (N_EDGES + N_NODES)   // with self-loops
#define IN_C 128
#define HID 64
#define HEADS 2
#define LAT 32
#define NEG_SLOPE 0.2f
#define MAXDEG 256     // max in-degree; Poisson(17) -> P(>200) ~ 0
#define NBUCKET 391    // ceil(N_NODES/128): coarse dst-buckets of 128 nodes
#define BCAP 3072      // bucket capacity; expect ~2176 +- 47 (20 sigma margin)
#define CHUNK 2048     // edges per scatter block (18KB LDS -> 8 blocks/CU)
#define NSCAT ((EP + CHUNK - 1) / CHUNK)   // 416 scatter blocks
#define NPROJ1 ((N_NODES + 31) / 32)       // 1563 proj1 blocks

typedef __attribute__((ext_vector_type(8))) short bf16x8;
typedef __attribute__((ext_vector_type(4))) float f32x4;

// fp32 -> bf16 round-to-nearest-even
__device__ __forceinline__ unsigned short f2bf(float f) {
  unsigned u = __float_as_uint(f);
  u += 0x7FFF + ((u >> 16) & 1);
  return (unsigned short)(u >> 16);
}
__device__ __forceinline__ float bf_lo(unsigned u) { return __uint_as_float(u << 16); }
__device__ __forceinline__ float bf_hi(unsigned u) { return __uint_as_float(u & 0xFFFF0000u); }

__device__ __forceinline__ bf16x8 pack_bf8(const float* __restrict__ p) {
  float4 a = *(const float4*)p;
  float4 b = *(const float4*)(p + 4);
  bf16x8 r;
  r[0] = (short)f2bf(a.x); r[1] = (short)f2bf(a.y);
  r[2] = (short)f2bf(a.z); r[3] = (short)f2bf(a.w);
  r[4] = (short)f2bf(b.x); r[5] = (short)f2bf(b.y);
  r[6] = (short)f2bf(b.z); r[7] = (short)f2bf(b.w);
  return r;
}

// ======= prep: zero cursors + pack W1/[Wmu|Wlv] into B-fragment layout ======
// Wb layout: [(kk*4+quad)*N + n]*8 + j  holds  W[k = kk*32+quad*8+j][n]
__global__ __launch_bounds__(256) void prep_kernel(
    const float* __restrict__ W1, const float* __restrict__ Wmu,
    const float* __restrict__ Wlv, int* __restrict__ cursor,
    unsigned short* __restrict__ Wb1g, unsigned short* __restrict__ Wb2g) {
  const int b = blockIdx.x, t = threadIdx.x;
  if (b == 0) {
    for (int i = t; i < NBUCKET; i += 256) cursor[i] = 0;
  } else if (b <= 64) {
    int i = (b - 1) * 256 + t;       // [0, 16384)
    int k = i >> 7, n = i & 127;
    int kk = k >> 5, q = (k >> 3) & 3, j = k & 7;
    Wb1g[((((kk << 2) + q) << 7) + n) * 8 + j] = f2bf(W1[i]);
  } else {
    int i = (b - 65) * 256 + t;      // [0, 8192)
    int k = i >> 6, n = i & 63;
    float v = (n < 32) ? Wmu[k * 32 + n] : Wlv[k * 32 + (n - 32)];
    int kk = k >> 5, q = (k >> 3) & 3, j = k & 7;
    Wb2g[((((kk << 2) + q) << 6) + n) * 8 + j] = f2bf(v);
  }
}

// ---------------- K1 shared-memory overlay (scatter | proj1) ----------------
struct ScatSmem {
  int histL[512];
  int baseL[512];
  int gbaseL[512];
  int wsumS[4];
  int nvalS;
  unsigned staging[CHUNK];
  unsigned short bktidL[CHUNK];
};
union K1Smem { ScatSmem sc; float part[32][4]; };

// ================= K1: bucket_scatter (blocks 0..NSCAT) =====================
// =================     proj1 (MFMA, global B-frags) + fused a1 ==============
__global__ __launch_bounds__(256) void k1_kernel(
    const int* __restrict__ ei, int* __restrict__ cursor,
    unsigned* __restrict__ csr,
    const float* __restrict__ x, const unsigned short* __restrict__ Wb1g,
    const float* __restrict__ att_src, const float* __restrict__ att_dst,
    unsigned short* __restrict__ h1b, float* __restrict__ a1) {
  __shared__ K1Smem sm;
  const int t = threadIdx.x, lane = t & 63, wid = t >> 6;

  if (blockIdx.x < NSCAT) {
    // ---------------- bucket scatter: LDS binning, chunked global writes ----
    for (int i = t; i < 512; i += 256) sm.sc.histL[i] = 0;
    __syncthreads();
    int myb[CHUNK / 256];
    int myloc[CHUNK / 256];
    unsigned mypay[CHUNK / 256];
    #pragma unroll
    for (int i = 0; i < CHUNK / 256; ++i) {
      int e = blockIdx.x * CHUNK + i * 256 + t;
      if (e < EP) {
        int s, d;
        if (e < N_EDGES) { s = ei[e]; d = ei[N_EDGES + e]; }
        else { s = d = e - N_EDGES; }
        int b = d >> 7;
        myb[i] = b;
        mypay[i] = ((unsigned)(d & 127) << 17) | (unsigned)s;  // s < 2^17
        myloc[i] = atomicAdd(&sm.sc.histL[b], 1);
      } else myb[i] = -1;
    }
    __syncthreads();
    {   // exclusive scan of histL[0..511]
      int v0 = sm.sc.histL[2 * t], v1 = sm.sc.histL[2 * t + 1];
      int pair = v0 + v1, inc = pair;
      #pragma unroll
      for (int off = 1; off < 64; off <<= 1) {
        int nv = __shfl_up(inc, off);
        if (lane >= off) inc += nv;
      }
      if (lane == 63) sm.sc.wsumS[wid] = inc;
      __syncthreads();
      if (t == 0) {
        int run = 0;
        #pragma unroll
        for (int w = 0; w < 4; ++w) { int c = sm.sc.wsumS[w]; sm.sc.wsumS[w] = run; run += c; }
        sm.sc.nvalS = run;
      }
      __syncthreads();
      int excl = sm.sc.wsumS[wid] + inc - pair;
      sm.sc.baseL[2 * t] = excl;
      sm.sc.baseL[2 * t + 1] = excl + v0;
    }
    __syncthreads();
    #pragma unroll
    for (int i = 0; i < CHUNK / 256; ++i)
      if (myb[i] >= 0) {
        int p = sm.sc.baseL[myb[i]] + myloc[i];
        sm.sc.staging[p] = mypay[i];
        sm.sc.bktidL[p] = (unsigned short)myb[i];
      }
    for (int b = t; b < NBUCKET; b += 256) {   // reserve chunks (relative)
      int c = sm.sc.histL[b];
      sm.sc.gbaseL[b] = c ? atomicAdd(&cursor[b], c) : 0;
    }
    __syncthreads();
    const int nval = sm.sc.nvalS;
    for (int j = t; j < nval; j += 256) {
      int b = sm.sc.bktidL[j];
      int off = sm.sc.gbaseL[b] + (j - sm.sc.baseL[b]);
      if (off < BCAP) csr[b * BCAP + off] = sm.sc.staging[j];  // overflow guard
    }
  } else {
    // ---------------- proj1 (MFMA) + fused a1 epilogue ----------------------
    const int pb = blockIdx.x - NSCAT;        // 0..NPROJ1-1
    if (t < 128) ((float*)sm.part)[t] = 0.f;
    __syncthreads();
    const int w = wid;
    const int m = lane & 15, quad = lane >> 4;
    const int row0 = pb * 32;
    const int n0 = w * 32;
    const int head = w >> 1;                  // cols n0.. all in one head
    f32x4 acc[2][2] = {};
    #pragma unroll
    for (int kk = 0; kk < 4; ++kk) {
      bf16x8 afr[2], bfr[2];
      #pragma unroll
      for (int mt = 0; mt < 2; ++mt) {
        int row = row0 + mt * 16 + m;
        if (row >= N_NODES) row = N_NODES - 1;
        afr[mt] = pack_bf8(x + (size_t)row * 128 + kk * 32 + quad * 8);
      }
      #pragma unroll
      for (int nt = 0; nt < 2; ++nt)
        bfr[nt] = *(const bf16x8*)&Wb1g[((((kk << 2) + quad) << 7) + n0 + nt * 16 + m) * 8];
      #pragma unroll
      for (int mt = 0; mt < 2; ++mt)
        #pragma unroll
        for (int nt = 0; nt < 2; ++nt)
          acc[mt][nt] = __builtin_amdgcn_mfma_f32_16x16x32_bf16(
              afr[mt], bfr[nt], acc[mt][nt], 0, 0, 0);
    }
    // per-lane att values for this wave's two 16-col groups (within head)
    float asv[2], adv[2];
    #pragma unroll
    for (int nt = 0; nt < 2; ++nt) {
      int cc = ((n0 & 63) + nt * 16 + m);
      asv[nt] = att_src[head * HID + cc];
      adv[nt] = att_dst[head * HID + cc];
    }
    #pragma unroll
    for (int mt = 0; mt < 2; ++mt)
      #pragma unroll
      for (int r = 0; r < 4; ++r) {
        int row = row0 + mt * 16 + quad * 4 + r;
        if (row < N_NODES) {
          #pragma unroll
          for (int nt = 0; nt < 2; ++nt)
            h1b[(size_t)row * 128 + n0 + nt * 16 + m] = f2bf(acc[mt][nt][r]);
        }
        float s = acc[mt][0][r] * asv[0] + acc[mt][1][r] * asv[1];
        float d = acc[mt][0][r] * adv[0] + acc[mt][1][r] * adv[1];
        #pragma unroll
        for (int off = 8; off; off >>= 1) {   // reduce 16 col-lanes (in-quad)
          s += __shfl_xor(s, off);
          d += __shfl_xor(d, off);
        }
        if (m == 0) {   // two waves per head accumulate
          atomicAdd(&sm.part[mt * 16 + quad * 4 + r][head], s);
          atomicAdd(&sm.part[mt * 16 + quad * 4 + r][2 + head], d);
        }
      }
    __syncthreads();
    if (t < 32) {
      int row = row0 + t;
      if (row < N_NODES)
        *(float4*)&a1[(size_t)row * 4] = make_float4(
            sm.part[t][0], sm.part[t][1], sm.part[t][2], sm.part[t][3]);
    }
  }
}

// Phase 2: one block per bucket; per-node histogram + prefix + in-place
// re-scatter within an L2-local 12 KB window.
__global__ __launch_bounds__(256) void bucket_fill_kernel(
    const int* __restrict__ cursor, unsigned* __restrict__ csr,
    int* __restrict__ counts, int* __restrict__ cend) {
  __shared__ unsigned eseg[BCAP];
  __shared__ int hist[128];
  __shared__ int basef[128];
  __shared__ int cur[128];
  const int b = blockIdx.x, t = threadIdx.x;
  const int segbase = b * BCAP;
  int cnt = cursor[b];
  if (cnt > BCAP) cnt = BCAP;
  if (t < 128) hist[t] = 0;
  __syncthreads();
  for (int j = t; j < cnt; j += 256) {
    unsigned u = csr[segbase + j];
    eseg[j] = u;
    atomicAdd(&hist[u >> 17], 1);
  }
  __syncthreads();
  if (t < 64) {   // exclusive scan of hist[0..127]
    int v0 = hist[2 * t], v1 = hist[2 * t + 1];
    int pair = v0 + v1, inc = pair;
    #pragma unroll
    for (int off = 1; off < 64; off <<= 1) {
      int nv = __shfl_up(inc, off);
      if (t >= off) inc += nv;
    }
    int excl = inc - pair;
    basef[2 * t] = excl;
    basef[2 * t + 1] = excl + v0;
  }
  __syncthreads();
  if (t < 128) {
    cur[t] = basef[t];
    int n = b * 128 + t;
    if (n < N_NODES) {
      counts[n] = hist[t];
      cend[n] = segbase + basef[t] + hist[t];
    }
  }
  __syncthreads();
  for (int j = t; j < cnt; j += 256) {
    unsigned u = eseg[j];
    int dl = u >> 17;
    int p = atomicAdd(&cur[dl], 1);
    csr[segbase + p] = u & 0x1FFFF;    // src id only
  }
}

// ---- layer-1 gather-aggregate: weights once per edge (LDS), bf16 gather ----
__global__ __launch_bounds__(64) void agg1_csr_kernel(
    const int* __restrict__ counts, const int* __restrict__ cend,
    const unsigned* __restrict__ csr_src, const float4* __restrict__ a1,
    const unsigned* __restrict__ h1b2, const float* __restrict__ b,
    float* __restrict__ hact) {
  __shared__ float w_lds[2][MAXDEG];
  __shared__ int   s_lds[MAXDEG];
  const int n = blockIdx.x;
  const int t = threadIdx.x;
  const int end = cend[n];
  int cnt = counts[n];
  if (cnt > MAXDEG) cnt = MAXDEG;
  const int beg = end - cnt;
  const float4 bv = a1[n];
  float p0 = 0.f, p1 = 0.f;
  for (int i = t; i < cnt; i += 64) {
    int s = (int)csr_src[beg + i];
    float4 av = a1[s];
    float l0 = av.x + bv.z; l0 = l0 > 0.f ? l0 : NEG_SLOPE * l0;
    float l1 = av.y + bv.w; l1 = l1 > 0.f ? l1 : NEG_SLOPE * l1;
    float e0 = expf(l0), e1 = expf(l1);
    w_lds[0][i] = e0; w_lds[1][i] = e1; s_lds[i] = s;
    p0 += e0; p1 += e1;
  }
  #pragma unroll
  for (int off = 32; off; off >>= 1) {
    p0 += __shfl_xor(p0, off);
    p1 += __shfl_xor(p1, off);
  }
  __syncthreads();
  const int head = t >> 5;
  const unsigned* hp = h1b2 + t;
  float ax = 0.f, ay = 0.f;
  #pragma unroll 4
  for (int i = 0; i < cnt; ++i) {
    int s = s_lds[i];
    float w = w_lds[head][i];
    unsigned u = hp[(size_t)s * 64];
    ax += bf_lo(u) * w; ay += bf_hi(u) * w;
  }
  float inv = 1.f / ((head ? p1 : p0) + 1e-16f);
  float vx = ax * inv + b[t * 2];
  float vy = ay * inv + b[t * 2 + 1];
  vx = vx > 0.f ? vx : (expf(vx) - 1.f);
  vy = vy > 0.f ? vy : (expf(vy) - 1.f);
  *(float2*)(hact + (size_t)n * 128 + t * 2) = make_float2(vx, vy);
}

// ------- proj2 (MFMA, global B-frags) + fused a2 ----------------------------
__global__ __launch_bounds__(256) void proj2_kernel(
    const float* __restrict__ h, const unsigned short* __restrict__ Wb2g,
    const float* __restrict__ asmu, const float* __restrict__ admu,
    const float* __restrict__ aslv, const float* __restrict__ adlv,
    unsigned short* __restrict__ h2b, float* __restrict__ a2) {
  const int t = threadIdx.x;
  const int w = t >> 6, lane = t & 63;
  const int m = lane & 15, quad = lane >> 4;
  const int row0 = blockIdx.x * 64 + (w >> 1) * 32;
  const int j = w & 1;                 // 0 = mu, 1 = lv
  const int n0 = j * 32;
  f32x4 acc[2][2] = {};
  #pragma unroll
  for (int kk = 0; kk < 4; ++kk) {
    bf16x8 afr[2], bfr[2];
    #pragma unroll
    for (int mt = 0; mt < 2; ++mt) {
      int row = row0 + mt * 16 + m;
      if (row >= N_NODES) row = N_NODES - 1;
      afr[mt] = pack_bf8(h + (size_t)row * 128 + kk * 32 + quad * 8);
    }
    #pragma unroll
    for (int nt = 0; nt < 2; ++nt)
      bfr[nt] = *(const bf16x8*)&Wb2g[((((kk << 2) + quad) << 6) + n0 + nt * 16 + m) * 8];
    #pragma unroll
    for (int mt = 0; mt < 2; ++mt)
      #pragma unroll
      for (int nt = 0; nt < 2; ++nt)
        acc[mt][nt] = __builtin_amdgcn_mfma_f32_16x16x32_bf16(
            afr[mt], bfr[nt], acc[mt][nt], 0, 0, 0);
  }
  float asv[2], adv[2];
  #pragma unroll
  for (int nt = 0; nt < 2; ++nt) {
    int o = nt * 16 + m;
    asv[nt] = (j ? aslv : asmu)[o];
    adv[nt] = (j ? adlv : admu)[o];
  }
  #pragma unroll
  for (int mt = 0; mt < 2; ++mt)
    #pragma unroll
    for (int r = 0; r < 4; ++r) {
      int row = row0 + mt * 16 + quad * 4 + r;
      if (row < N_NODES) {
        #pragma unroll
        for (int nt = 0; nt < 2; ++nt)
          h2b[(size_t)row * 64 + n0 + nt * 16 + m] = f2bf(acc[mt][nt][r]);
      }
      float s = acc[mt][0][r] * asv[0] + acc[mt][1][r] * asv[1];
      float d = acc[mt][0][r] * adv[0] + acc[mt][1][r] * adv[1];
      #pragma unroll
      for (int off = 8; off; off >>= 1) {   // reduce 16 col-lanes
        s += __shfl_xor(s, off);
        d += __shfl_xor(d, off);
      }
      if (m == 0 && row < N_NODES) {
        a2[(size_t)row * 4 + j * 2 + 0] = s;   // (s_mu, d_mu, s_lv, d_lv)
        a2[(size_t)row * 4 + j * 2 + 1] = d;
      }
    }
}

// ---- layer-2 gather-aggregate: 2 nodes/block, 32 lanes each, bf16 pairs ----
__global__ __launch_bounds__(64) void agg2_csr_kernel(
    const int* __restrict__ counts, const int* __restrict__ cend,
    const unsigned* __restrict__ csr_src, const float4* __restrict__ a2,
    const unsigned* __restrict__ h2b2,
    const float* __restrict__ bmu, const float* __restrict__ blv,
    float* __restrict__ out) {
  __shared__ float w_lds[2][2][MAXDEG];
  __shared__ int   s_lds[2][MAXDEG];
  const int t = threadIdx.x, half = t >> 5, hl = t & 31;
  const int n = blockIdx.x * 2 + half;
  const int end = cend[n];
  int cnt = counts[n];
  if (cnt > MAXDEG) cnt = MAXDEG;
  const int beg = end - cnt;
  const float4 bv = a2[n];
  float p0 = 0.f, p1 = 0.f;
  for (int i = hl; i < cnt; i += 32) {
    int s = (int)csr_src[beg + i];
    float4 av = a2[s];
    float l0 = av.x + bv.y; l0 = l0 > 0.f ? l0 : NEG_SLOPE * l0;  // mu
    float l1 = av.z + bv.w; l1 = l1 > 0.f ? l1 : NEG_SLOPE * l1;  // lv
    float e0 = expf(l0), e1 = expf(l1);
    w_lds[half][0][i] = e0; w_lds[half][1][i] = e1; s_lds[half][i] = s;
    p0 += e0; p1 += e1;
  }
  #pragma unroll
  for (int off = 16; off; off >>= 1) {   // butterfly within 32-lane half
    p0 += __shfl_xor(p0, off);
    p1 += __shfl_xor(p1, off);
  }
  __syncthreads();
  const int c0 = 2 * hl;             // channels (c0, c0+1) of the h2 row
  const int j = c0 >> 5;             // 0 = mu, 1 = lv
  const int o = c0 & 31;
  const unsigned* hp = h2b2 + hl;
  float ax = 0.f, ay = 0.f;
  #pragma unroll 4
  for (int i = 0; i < cnt; ++i) {
    int s = s_lds[half][i];
    float w = w_lds[half][j][i];
    unsigned u = hp[(size_t)s * 32];
    ax += bf_lo(u) * w; ay += bf_hi(u) * w;
  }
  float inv = 1.f / ((j ? p1 : p0) + 1e-16f);
  const float* bb = j ? blv : bmu;
  *(float2*)&out[(size_t)j * N_NODES * LAT + (size_t)n * LAT + o] =
      make_float2(ax * inv + bb[o], ay * inv + bb[o + 1]);
}

extern "C" void kernel_launch(void* const* d_in, const int* in_sizes, int n_in,
                              void* d_out, int out_size, void* d_ws, size_t ws_size,
                              hipStream_t stream) {
  const float* x        = (const float*)d_in[0];
  const int* ei         = (const int*)d_in[1];   // int32 per harness contract
  const float* W1       = (const float*)d_in[2];
  const float* att_src1 = (const float*)d_in[3];
  const float* att_dst1 = (const float*)d_in[4];
  const float* b1       = (const float*)d_in[5];
  const float* Wmu      = (const float*)d_in[6];
  const float* asmu     = (const float*)d_in[7];
  const float* admu     = (const float*)d_in[8];
  const float* bmu      = (const float*)d_in[9];
  const float* Wlv      = (const float*)d_in[10];
  const float* aslv     = (const float*)d_in[11];
  const float* adlv     = (const float*)d_in[12];
  const float* blv      = (const float*)d_in[13];
  float* out = (float*)d_out;

  // workspace layout (4-B units) — all 16-B-vector-loaded buffers 16-B aligned:
  //  [hact N*128 | a1 N*4 | a2 N*4 | h1b N*64(bf16 pairs) | h2b N*32 |
  //   Wb1g 4096 | Wb2g 2048 | counts N | cend N | cursor NBUCKET | csr N_B*BCAP]
  float* ws   = (float*)d_ws;
  float* hact = ws;
  float* a1   = hact + (size_t)N_NODES * 128;
  float* a2   = a1 + (size_t)N_NODES * 4;
  unsigned short* h1b = (unsigned short*)(a2 + (size_t)N_NODES * 4);
  unsigned short* h2b = h1b + (size_t)N_NODES * 128;
  unsigned short* Wb1g = h2b + (size_t)N_NODES * 64;   // byte off 46,400,000 (16-aligned)
  unsigned short* Wb2g = Wb1g + 16384;                  // +32 KB (16-aligned)
  int* counts = (int*)(Wb2g + 8192);
  int* cend   = counts + N_NODES;
  int* cursor = cend + N_NODES;
  unsigned* csr = (unsigned*)(cursor + NBUCKET);

  // prep: zero cursors + pack both weight matrices into B-frag layout
  prep_kernel<<<97, 256, 0, stream>>>(W1, Wmu, Wlv, cursor, Wb1g, Wb2g);

  // K1: bucket_scatter (416 blocks) || proj1+a1 (1563 blocks)
  k1_kernel<<<NSCAT + NPROJ1, 256, 0, stream>>>(
      ei, cursor, csr, x, Wb1g, att_src1, att_dst1, h1b, a1);
  bucket_fill_kernel<<<NBUCKET, 256, 0, stream>>>(cursor, csr, counts, cend);
  agg1_csr_kernel<<<N_NODES, 64, 0, stream>>>(
      counts, cend, csr, (const float4*)a1, (const unsigned*)h1b, b1, hact);
  proj2_kernel<<<(N_NODES + 63) / 64, 256, 0, stream>>>(
      hact, Wb2g, asmu, admu, aslv, adlv, h2b, a2);
  agg2_csr_kernel<<<N_NODES / 2, 64, 0, stream>>>(
      counts, cend, csr, (const float4*)a2, (const unsigned*)h2b, bmu, blv, out);
}